// Round 1
// baseline (760.862 us; speedup 1.0000x reference)
//
#include <hip/hip_runtime.h>
#include <cstdint>
#include <cstddef>

typedef __attribute__((ext_vector_type(4))) float     f32x4;
typedef __attribute__((ext_vector_type(8))) __bf16    bf16x8;
typedef __attribute__((ext_vector_type(8))) short     short8;
typedef __attribute__((ext_vector_type(4))) unsigned short u16x4;
typedef unsigned short u16;

__device__ __forceinline__ float b2f(u16 u) {
  unsigned x = ((unsigned)u) << 16;
  float f;
  __builtin_memcpy(&f, &x, 4);
  return f;
}
__device__ __forceinline__ u16 f2b(float f) {
  unsigned u;
  __builtin_memcpy(&u, &f, 4);
  return (u16)((u + 0x7FFFu + ((u >> 16) & 1u)) >> 16);
}

// ---------------------------------------------------------------------------
// Generic implicit-GEMM / GEMM kernel.
//   C[m, n] = sum_k A[m, k] * B^T[n, k]   (fp32 accum, bf16 operands)
// A: AMODE==0 flat [Mrows][Ktot] bf16 (row clamped to Mrows-1)
//    AMODE==1 padded NHWC image: row m -> pixel (y,x); k = tap*cin + ci
// B: [N][Ktot] bf16 flat (weights or activation)
// Tile: 128(M) x 128(N) x 64(K); 4 waves (2x2), each 64x64 via 4x4 MFMA frags.
// ---------------------------------------------------------------------------
struct GP {
  const u16*  A;
  const u16*  B;
  const float* bias;     // may be null
  const void* aux;       // CW2: S (u16), CW6: mid (float)
  void*       C;
  float*      out0;      // CW4 row-0 destination
  long long   aBS, bBS, cBS, auxBS;  // per-batch strides in ELEMENTS
  int Ktot, Mrows, ldc;
  int cin, logW, wpad, poff;
  float scale;
};

#define GLDS16(g, l)                                                        \
  __builtin_amdgcn_global_load_lds(                                         \
      (const void __attribute__((address_space(1)))*)(g),                   \
      (void __attribute__((address_space(3)))*)(l), 16, 0, 0)

template <int AMODE, int CW, bool RELU>
__global__ __launch_bounds__(256, 2) void k_gemm(GP gp) {
  const int tid = threadIdx.x;
  const int l = tid & 63, w = tid >> 6;
  const int b = blockIdx.z;
  const int m0 = blockIdx.x * 128, n0 = blockIdx.y * 128;
  const int wm = w >> 1, wn = w & 1;

  __shared__ __align__(16) u16 smA[128 * 64];
  __shared__ __align__(16) u16 smB[128 * 64];

  f32x4 acc[4][4];
#pragma unroll
  for (int i = 0; i < 4; ++i)
#pragma unroll
    for (int j = 0; j < 4; ++j) acc[i][j] = (f32x4){0.f, 0.f, 0.f, 0.f};

  const u16* Ab = gp.A + (size_t)b * gp.aBS;
  const u16* Bb = gp.B + (size_t)b * gp.bBS;

  // source swizzle: chunk (l&7) of each 8-row group loads global chunk (l&7)^(l>>3)
  const int scoff = (((l & 7) ^ (l >> 3)) << 3);  // element offset

  const u16* aRow[4];
  const u16* bRow[4];
  u16* ldsA[4];
  u16* ldsB[4];
#pragma unroll
  for (int i = 0; i < 4; ++i) {
    const int r = w * 32 + i * 8 + (l >> 3);
    bRow[i] = Bb + (size_t)(n0 + r) * gp.Ktot + scoff;
    const int p = m0 + r;
    if (AMODE == 0) {
      const int pc = p < gp.Mrows ? p : gp.Mrows - 1;
      aRow[i] = Ab + (size_t)pc * gp.Ktot + scoff;
    } else {
      const int y = p >> gp.logW, x = p & ((1 << gp.logW) - 1);
      const int icoord = (y + gp.poff) * gp.wpad + (x + gp.poff);
      aRow[i] = Ab + (size_t)icoord * gp.cin + scoff;
    }
    ldsA[i] = smA + (w * 32 + i * 8) * 64;
    ldsB[i] = smB + (w * 32 + i * 8) * 64;
  }

  const int ktiles = gp.Ktot >> 6;
  int tap_off = 0, dx = 0, kc = 0;

  for (int kt = 0; kt < ktiles; ++kt) {
    int koffA;
    if (AMODE == 0)
      koffA = kt << 6;
    else
      koffA = tap_off * gp.cin + kc;
    const int koffB = kt << 6;
#pragma unroll
    for (int i = 0; i < 4; ++i) GLDS16(aRow[i] + koffA, ldsA[i]);
#pragma unroll
    for (int i = 0; i < 4; ++i) GLDS16(bRow[i] + koffB, ldsB[i]);

    if (AMODE == 1) {
      kc += 64;
      if (kc == gp.cin) {
        kc = 0;
        ++dx;
        ++tap_off;
        if (dx == 3) { dx = 0; tap_off += gp.wpad - 3; }
      }
    }

    __syncthreads();
#pragma unroll
    for (int ks = 0; ks < 2; ++ks) {
      bf16x8 av[4], bv[4];
      const int cc = (ks << 2) + (l >> 4);
#pragma unroll
      for (int mi = 0; mi < 4; ++mi) {
        const int row = wm * 64 + mi * 16 + (l & 15);
        av[mi] = *(const bf16x8*)((const char*)smA + (row << 7) +
                                  ((cc ^ (row & 7)) << 4));
      }
#pragma unroll
      for (int ni = 0; ni < 4; ++ni) {
        const int row = wn * 64 + ni * 16 + (l & 15);
        bv[ni] = *(const bf16x8*)((const char*)smB + (row << 7) +
                                  ((cc ^ (row & 7)) << 4));
      }
#pragma unroll
      for (int mi = 0; mi < 4; ++mi)
#pragma unroll
        for (int ni = 0; ni < 4; ++ni)
          acc[mi][ni] = __builtin_amdgcn_mfma_f32_16x16x32_bf16(
              av[mi], bv[ni], acc[mi][ni], 0, 0, 0);
    }
    __syncthreads();
  }

  // ------------------------- epilogue / C write ---------------------------
#pragma unroll
  for (int mi = 0; mi < 4; ++mi) {
#pragma unroll
    for (int ni = 0; ni < 4; ++ni) {
      const int ncol = n0 + wn * 64 + ni * 16 + (l & 15);
      const int mbase = m0 + wm * 64 + mi * 16 + ((l >> 4) << 2);
      const float bv_ = gp.bias ? gp.bias[ncol] : 0.f;

      if constexpr (CW == 3) {
        // bf16 "NCHW": C[ncol][m], 4 consecutive m -> 8B store
        u16* Cu = (u16*)gp.C + (size_t)b * gp.cBS + (size_t)ncol * 4096 + mbase;
        u16x4 pk;
#pragma unroll
        for (int r = 0; r < 4; ++r) pk[r] = f2b(acc[mi][ni][r] + bv_);
        *(u16x4*)Cu = pk;
      } else if constexpr (CW == 6) {
        // final: relu(acc+bias) + mid, fp32 NCHW into d_out
        float* Cf = (float*)gp.C + (size_t)b * gp.cBS + (size_t)ncol * 4096 + mbase;
        const float* mid = (const float*)gp.aux + (size_t)b * gp.auxBS;
        f32x4 o;
#pragma unroll
        for (int r = 0; r < 4; ++r) {
          float v = acc[mi][ni][r] + bv_;
          v = v > 0.f ? v : 0.f;
          o[r] = v + mid[(size_t)(mbase + r) * 256 + ncol];
        }
        *(f32x4*)Cf = o;
      } else {
#pragma unroll
        for (int reg = 0; reg < 4; ++reg) {
          const int mrow = mbase + reg;
          if (mrow >= gp.Mrows) continue;
          float v = acc[mi][ni][reg] * gp.scale + bv_;
          if (RELU) v = v > 0.f ? v : 0.f;
          if constexpr (CW == 0) {
            ((u16*)gp.C)[(size_t)b * gp.cBS + (size_t)mrow * gp.ldc + ncol] =
                f2b(v);
          } else if constexpr (CW == 1) {
            const int y = mrow >> 6, x = mrow & 63;
            ((u16*)gp.C)[(size_t)b * gp.cBS +
                         (size_t)((y + 1) * 66 + (x + 1)) * 256 + ncol] = f2b(v);
          } else if constexpr (CW == 2) {
            const float s =
                b2f(((const u16*)gp.aux)[(size_t)b * gp.auxBS +
                                         (size_t)mrow * 256 + ncol]);
            float v2 = v + s;
            v2 = v2 > 0.f ? v2 : 0.f;
            ((float*)gp.C)[(size_t)b * gp.cBS + (size_t)mrow * 256 + ncol] = v2;
          } else if constexpr (CW == 4) {
            if (mrow == 0) {
              gp.out0[(size_t)b * 256 + ncol] = v;
            } else {
              const int p = mrow - 1, y = p >> 5, x = p & 31;
              ((u16*)gp.C)[(size_t)b * gp.cBS +
                           (size_t)((y + 1) * 34 + (x + 1)) * 256 + ncol] =
                  f2b(v);
            }
          } else if constexpr (CW == 5) {
            ((float*)gp.C)[(size_t)b * gp.cBS + (size_t)mrow * 256 + ncol] = v;
          }
        }
      }
    }
  }
}

// --------------------------- prep / misc kernels ---------------------------

// NCHW fp32 (8,1280,64,64) -> padded NHWC bf16 (8,66,66,1280)
__global__ __launch_bounds__(256) void k_prep_x(const float* __restrict__ x,
                                                u16* __restrict__ o) {
  __shared__ float t[32][65];
  const int b = blockIdx.z, c0 = blockIdx.y << 5, y = blockIdx.x;
  const float* src = x + ((size_t)b * 1280 + c0) * 4096 + (size_t)y * 64;
#pragma unroll
  for (int i = 0; i < 8; ++i) {
    const int idx = threadIdx.x + (i << 8);
    const int c = idx >> 6, xx = idx & 63;
    t[c][xx] = src[(size_t)c * 4096 + xx];
  }
  __syncthreads();
  u16* dst = o + ((size_t)b * 4356 + (size_t)(y + 1) * 66 + 1) * 1280 + c0;
#pragma unroll
  for (int i = 0; i < 8; ++i) {
    const int idx = threadIdx.x + (i << 8);
    const int xx = idx >> 5, c = idx & 31;
    dst[(size_t)xx * 1280 + c] = f2b(t[c][xx]);
  }
}

// W[co][ci][3][3] fp32 -> W_r[co][tap][ci] bf16
__global__ __launch_bounds__(256) void k_prep_w3(const float* __restrict__ w,
                                                 u16* __restrict__ o, int cin,
                                                 int n) {
  for (int i = blockIdx.x * 256 + threadIdx.x; i < n; i += gridDim.x * 256) {
    const int ci = i % cin;
    const int r = i / cin;
    const int t = r % 9;
    const int co = r / 9;
    o[i] = f2b(w[((size_t)co * cin + ci) * 9 + t]);
  }
}

__global__ __launch_bounds__(256) void k_f2b(const float* __restrict__ x,
                                             u16* __restrict__ o, int n) {
  for (int i = blockIdx.x * 256 + threadIdx.x; i < n; i += gridDim.x * 256)
    o[i] = f2b(x[i]);
}

// per-batch sum / sumsq over 1048576 fp32 elements
__global__ __launch_bounds__(256) void k_gn_stats(const float* __restrict__ x,
                                                  float* __restrict__ st) {
  const int b = blockIdx.y;
  const f32x4* xb = (const f32x4*)(x + (size_t)b * 1048576);
  float s = 0.f, s2 = 0.f;
  for (int i = blockIdx.x * 256 + threadIdx.x; i < 262144;
       i += gridDim.x * 256) {
    const f32x4 v = xb[i];
    s += v[0] + v[1] + v[2] + v[3];
    s2 += v[0] * v[0] + v[1] * v[1] + v[2] * v[2] + v[3] * v[3];
  }
#pragma unroll
  for (int o = 32; o; o >>= 1) {
    s += __shfl_down(s, o);
    s2 += __shfl_down(s2, o);
  }
  __shared__ float ls[4], ls2[4];
  const int w = threadIdx.x >> 6;
  if ((threadIdx.x & 63) == 0) { ls[w] = s; ls2[w] = s2; }
  __syncthreads();
  if (threadIdx.x == 0) {
    atomicAdd(&st[b * 2], ls[0] + ls[1] + ls[2] + ls[3]);
    atomicAdd(&st[b * 2 + 1], ls2[0] + ls2[1] + ls2[2] + ls2[3]);
  }
}

// normalize: (x-mu)*rsqrt(var+eps)*g + b -> bf16, flat NHWC or 66-padded NHWC
template <bool PAD>
__global__ __launch_bounds__(256) void k_gn_norm(const float* __restrict__ x,
                                                 const float* __restrict__ st,
                                                 const float* __restrict__ g,
                                                 const float* __restrict__ bb,
                                                 u16* __restrict__ o) {
  const int b = blockIdx.y;
  const float mu = st[b * 2] * (1.f / 1048576.f);
  const float var = st[b * 2 + 1] * (1.f / 1048576.f) - mu * mu;
  const float rs = rsqrtf(var + 1e-6f);
  const int i4 = blockIdx.x * 256 + threadIdx.x;  // grid.x = 1024 exact
  const f32x4 v = ((const f32x4*)(x + (size_t)b * 1048576))[i4];
  const int flat = i4 << 2;
  const int c = flat & 255;
  const int p = flat >> 8;
  const f32x4 gv = *(const f32x4*)(g + c);
  const f32x4 bv = *(const f32x4*)(bb + c);
  u16x4 r;
#pragma unroll
  for (int k = 0; k < 4; ++k) r[k] = f2b((v[k] - mu) * rs * gv[k] + bv[k]);
  size_t oidx;
  if (PAD) {
    const int y = p >> 6, xx = p & 63;
    oidx = ((size_t)b * 4356 + (size_t)(y + 1) * 66 + xx + 1) * 256 + c;
  } else {
    oidx = ((size_t)b * 4096 + p) * 256 + c;
  }
  *(u16x4*)(o + oidx) = r;
}

// in-place row softmax over 4096 bf16 values
__global__ __launch_bounds__(256) void k_softmax(u16* __restrict__ s) {
  const size_t row = blockIdx.x;
  u16* p = s + row * 4096;
  const int t = threadIdx.x;
  const short8 r0 = ((const short8*)p)[t];
  const short8 r1 = ((const short8*)p)[t + 256];
  float v[16];
#pragma unroll
  for (int i = 0; i < 8; ++i) {
    v[i] = b2f((u16)r0[i]);
    v[8 + i] = b2f((u16)r1[i]);
  }
  float m = v[0];
#pragma unroll
  for (int i = 1; i < 16; ++i) m = fmaxf(m, v[i]);
#pragma unroll
  for (int o = 32; o; o >>= 1) m = fmaxf(m, __shfl_xor(m, o));
  __shared__ float lm[4], lsum[4];
  const int w = t >> 6;
  if ((t & 63) == 0) lm[w] = m;
  __syncthreads();
  m = fmaxf(fmaxf(lm[0], lm[1]), fmaxf(lm[2], lm[3]));
  float sum = 0.f;
#pragma unroll
  for (int i = 0; i < 16; ++i) {
    v[i] = __expf(v[i] - m);
    sum += v[i];
  }
#pragma unroll
  for (int o = 32; o; o >>= 1) sum += __shfl_xor(sum, o);
  if ((t & 63) == 0) lsum[w] = sum;
  __syncthreads();
  sum = lsum[0] + lsum[1] + lsum[2] + lsum[3];
  const float inv = 1.f / sum;
  short8 o0, o1;
#pragma unroll
  for (int i = 0; i < 8; ++i) {
    o0[i] = (short)f2b(v[i] * inv);
    o1[i] = (short)f2b(v[8 + i] * inv);
  }
  ((short8*)p)[t] = o0;
  ((short8*)p)[t + 256] = o1;
}

// bilinear 32->64 (align-corners) + add F -> mid  (all NHWC fp32)
__global__ __launch_bounds__(256) void k_resize_add(const float* __restrict__ d0,
                                                    const float* __restrict__ F,
                                                    float* __restrict__ mid) {
  const int i4 = blockIdx.x * 256 + threadIdx.x;  // grid.x = 8192 exact
  const int flat = i4 << 2;
  const int c = flat & 255;
  const int p = (flat >> 8) & 4095;
  const int b = flat >> 20;
  const int y = p >> 6, x = p & 63;
  const float fy = y * (31.f / 63.f);
  const int y0 = (int)fy;
  const float wy = fy - y0;
  const int y1 = y0 + 1 > 31 ? 31 : y0 + 1;
  const float fx = x * (31.f / 63.f);
  const int x0 = (int)fx;
  const float wx = fx - x0;
  const int x1 = x0 + 1 > 31 ? 31 : x0 + 1;
  const float* db = d0 + (size_t)b * 262144;
  const f32x4 a = *(const f32x4*)(db + ((size_t)(y0 * 32 + x0) << 8) + c);
  const f32x4 bq = *(const f32x4*)(db + ((size_t)(y0 * 32 + x1) << 8) + c);
  const f32x4 cq = *(const f32x4*)(db + ((size_t)(y1 * 32 + x0) << 8) + c);
  const f32x4 dq = *(const f32x4*)(db + ((size_t)(y1 * 32 + x1) << 8) + c);
  f32x4 r = (a * (1.f - wx) + bq * wx) * (1.f - wy) +
            (cq * (1.f - wx) + dq * wx) * wy;
  r += *(const f32x4*)(F + (size_t)flat);
  *(f32x4*)(mid + (size_t)flat) = r;
}

// ---------------------------------------------------------------------------

extern "C" void kernel_launch(void* const* d_in, const int* in_sizes, int n_in,
                              void* d_out, int out_size, void* d_ws,
                              size_t ws_size, hipStream_t stream) {
  (void)in_sizes; (void)n_in; (void)out_size;

  const float* q   = (const float*)d_in[0];
  const float* xdc = (const float*)d_in[1];
  const float* w1  = (const float*)d_in[2];
  const float* b1  = (const float*)d_in[3];
  const float* w2  = (const float*)d_in[4];
  const float* b2  = (const float*)d_in[5];
  const float* wsc = (const float*)d_in[6];
  const float* bsc = (const float*)d_in[7];
  const float* lng = (const float*)d_in[8];
  const float* lnb = (const float*)d_in[9];
  const float* wk  = (const float*)d_in[10];
  const float* bk  = (const float*)d_in[11];
  const float* wv  = (const float*)d_in[12];
  const float* bv  = (const float*)d_in[13];
  const float* wd0 = (const float*)d_in[14];
  const float* bd0 = (const float*)d_in[15];
  const float* wd1 = (const float*)d_in[16];
  const float* bd1 = (const float*)d_in[17];

  char* ws = (char*)d_ws;
  size_t cur = 0;
  auto alloc = [&](size_t sz) {
    char* p = ws + cur;
    cur += sz;
    return p;
  };
  u16* XPAD = (u16*)alloc(89194496);   // 8*66*66*1280 bf16; reused for scores
  u16* W1R  = (u16*)alloc(5898240);    // 256*9*1280
  u16* W2R  = (u16*)alloc(1179648);    // 256*9*256
  u16* WSR  = (u16*)alloc(655360);     // 256*1280
  u16* WKR  = (u16*)alloc(131072);
  u16* WVR  = (u16*)alloc(131072);
  u16* WD0R = (u16*)alloc(1179648);
  u16* WD1R = (u16*)alloc(1179648);
  u16* SB   = (u16*)alloc(16777216);   // shortcut, NHWC bf16
  u16* H1   = (u16*)alloc(17842176);   // conv1 out, padded NHWC bf16
  float* F  = (float*)alloc(33554432); // feat_diff NHWC fp32
  u16* FLN  = (u16*)alloc(16777216);   // gn1 out NHWC bf16
  u16* KT   = (u16*)alloc(16777216);   // key, [pixel][d]
  u16* V    = (u16*)alloc(16777216);   // value, [f][pixel]
  u16* QB   = (u16*)alloc(4198400);    // query bf16 [1025][256]
  u16* OCP  = (u16*)alloc(4734976);    // attn spatial out, 34x34 padded NHWC
  float* D0O = (float*)alloc(8388608); // dh0 out NHWC fp32 (32x32)
  float* MID = (float*)alloc(33554432);// out_p mid NHWC fp32
  u16* G2   = (u16*)alloc(17842176);   // gn2 out, padded NHWC bf16
  float* ST = (float*)alloc(256);      // [0:16) gn1, [16:32) gn2
  u16* SCORES = XPAD;                  // alias (X_pad dead after conv1/shortcut)

  if (ws_size < cur) return;  // insufficient scratch: fail loudly (no writes)

  float* out0 = (float*)d_out;           // (8,1,256)
  float* out1 = (float*)d_out + 2048;    // (8,256,64,64) NCHW

  hipMemsetAsync(XPAD, 0, 89194496, stream);
  hipMemsetAsync(H1, 0, 17842176, stream);
  hipMemsetAsync(OCP, 0, 4734976, stream);
  hipMemsetAsync(G2, 0, 17842176, stream);
  hipMemsetAsync(ST, 0, 256, stream);

  k_prep_x<<<dim3(64, 40, 8), 256, 0, stream>>>(xdc, XPAD);
  k_prep_w3<<<2048, 256, 0, stream>>>(w1, W1R, 1280, 2949120);
  k_prep_w3<<<1024, 256, 0, stream>>>(w2, W2R, 256, 589824);
  k_prep_w3<<<1024, 256, 0, stream>>>(wd0, WD0R, 256, 589824);
  k_prep_w3<<<1024, 256, 0, stream>>>(wd1, WD1R, 256, 589824);
  k_f2b<<<512, 256, 0, stream>>>(wsc, WSR, 327680);
  k_f2b<<<128, 256, 0, stream>>>(wk, WKR, 65536);
  k_f2b<<<128, 256, 0, stream>>>(wv, WVR, 65536);
  k_f2b<<<2048, 256, 0, stream>>>(q, QB, 2099200);

  // shortcut 1x1: X_pad(interior) x WSR -> SB (bf16, +bias, no relu)
  {
    GP g{};
    g.A = XPAD; g.B = WSR; g.bias = bsc; g.C = SB;
    g.aBS = 5575680; g.bBS = 0; g.cBS = 1048576;
    g.Ktot = 1280; g.Mrows = 4096; g.ldc = 256;
    g.cin = 1280; g.logW = 6; g.wpad = 66; g.poff = 1; g.scale = 1.f;
    k_gemm<1, 0, false><<<dim3(32, 2, 8), 256, 0, stream>>>(g);
  }
  // conv1 3x3: X_pad x W1R -> H1 (padded bf16, relu)
  {
    GP g{};
    g.A = XPAD; g.B = W1R; g.bias = b1; g.C = H1;
    g.aBS = 5575680; g.bBS = 0; g.cBS = 1115136;
    g.Ktot = 11520; g.Mrows = 4096; g.ldc = 256;
    g.cin = 1280; g.logW = 6; g.wpad = 66; g.poff = 0; g.scale = 1.f;
    k_gemm<1, 1, true><<<dim3(32, 2, 8), 256, 0, stream>>>(g);
  }
  // conv2 3x3: H1 x W2R (+bias +SB, relu) -> F fp32
  {
    GP g{};
    g.A = H1; g.B = W2R; g.bias = b2; g.C = F; g.aux = SB;
    g.aBS = 1115136; g.bBS = 0; g.cBS = 1048576; g.auxBS = 1048576;
    g.Ktot = 2304; g.Mrows = 4096; g.ldc = 256;
    g.cin = 256; g.logW = 6; g.wpad = 66; g.poff = 0; g.scale = 1.f;
    k_gemm<1, 2, false><<<dim3(32, 2, 8), 256, 0, stream>>>(g);
  }
  // gn1
  k_gn_stats<<<dim3(64, 8), 256, 0, stream>>>(F, ST);
  k_gn_norm<false><<<dim3(1024, 8), 256, 0, stream>>>(F, ST, lng, lnb, FLN);
  // key 1x1 -> KT [pixel][256]
  {
    GP g{};
    g.A = FLN; g.B = WKR; g.bias = bk; g.C = KT;
    g.aBS = 1048576; g.bBS = 0; g.cBS = 1048576;
    g.Ktot = 256; g.Mrows = 4096; g.ldc = 256; g.scale = 1.f;
    k_gemm<0, 0, false><<<dim3(32, 2, 8), 256, 0, stream>>>(g);
  }
  // value 1x1 -> V [f][pixel]
  {
    GP g{};
    g.A = FLN; g.B = WVR; g.bias = bv; g.C = V;
    g.aBS = 1048576; g.bBS = 0; g.cBS = 1048576;
    g.Ktot = 256; g.Mrows = 4096; g.ldc = 256; g.scale = 1.f;
    k_gemm<0, 3, false><<<dim3(32, 2, 8), 256, 0, stream>>>(g);
  }
  // scores: QB x KT^T * (1/16) -> SCORES bf16 [1025][4096]
  {
    GP g{};
    g.A = QB; g.B = KT; g.bias = nullptr; g.C = SCORES;
    g.aBS = 262400; g.bBS = 1048576; g.cBS = 4198400;
    g.Ktot = 256; g.Mrows = 1025; g.ldc = 4096; g.scale = 0.0625f;
    k_gemm<0, 0, false><<<dim3(9, 32, 8), 256, 0, stream>>>(g);
  }
  k_softmax<<<8200, 256, 0, stream>>>(SCORES);
  // attn out: SCORES x V^T -> row0 to d_out, rows 1..1024 to OCP (34x34 pad)
  {
    GP g{};
    g.A = SCORES; g.B = V; g.bias = nullptr; g.C = OCP; g.out0 = out0;
    g.aBS = 4198400; g.bBS = 1048576; g.cBS = 295936;
    g.Ktot = 4096; g.Mrows = 1025; g.ldc = 256; g.scale = 1.f;
    k_gemm<0, 4, false><<<dim3(9, 2, 8), 256, 0, stream>>>(g);
  }
  // dh0 3x3 @32x32: OCP x WD0R (+bias, relu) -> D0O fp32
  {
    GP g{};
    g.A = OCP; g.B = WD0R; g.bias = bd0; g.C = D0O;
    g.aBS = 295936; g.bBS = 0; g.cBS = 262144;
    g.Ktot = 2304; g.Mrows = 1024; g.ldc = 256;
    g.cin = 256; g.logW = 5; g.wpad = 34; g.poff = 0; g.scale = 1.f;
    k_gemm<1, 5, true><<<dim3(8, 2, 8), 256, 0, stream>>>(g);
  }
  // bilinear upsample + add F -> MID
  k_resize_add<<<8192, 256, 0, stream>>>(D0O, F, MID);
  // gn2
  k_gn_stats<<<dim3(64, 8), 256, 0, stream>>>(MID, ST + 16);
  k_gn_norm<true><<<dim3(1024, 8), 256, 0, stream>>>(MID, ST + 16, lng, lnb, G2);
  // dh1 3x3: G2 x WD1R, relu(acc+bias)+MID -> out1 (NCHW fp32)
  {
    GP g{};
    g.A = G2; g.B = WD1R; g.bias = bd1; g.C = out1; g.aux = MID;
    g.aBS = 1115136; g.bBS = 0; g.cBS = 1048576; g.auxBS = 1048576;
    g.Ktot = 2304; g.Mrows = 4096; g.ldc = 256;
    g.cin = 256; g.logW = 6; g.wpad = 66; g.poff = 0; g.scale = 1.f;
    k_gemm<1, 6, false><<<dim3(32, 2, 8), 256, 0, stream>>>(g);
  }
}

// Round 2
// 743.720 us; speedup vs baseline: 1.0230x; 1.0230x over previous
//
#include <hip/hip_runtime.h>
#include <cstdint>
#include <cstddef>

typedef __attribute__((ext_vector_type(4))) float     f32x4;
typedef __attribute__((ext_vector_type(8))) __bf16    bf16x8;
typedef __attribute__((ext_vector_type(8))) short     short8;
typedef __attribute__((ext_vector_type(4))) unsigned short u16x4;
typedef unsigned short u16;

__device__ __forceinline__ float b2f(u16 u) {
  unsigned x = ((unsigned)u) << 16;
  float f;
  __builtin_memcpy(&f, &x, 4);
  return f;
}
__device__ __forceinline__ u16 f2b(float f) {
  unsigned u;
  __builtin_memcpy(&u, &f, 4);
  return (u16)((u + 0x7FFFu + ((u >> 16) & 1u)) >> 16);
}

struct GP {
  const u16*  A;
  const u16*  B;
  const float* bias;     // may be null
  const void* aux;       // CW2: S (u16), CW6: mid (float)
  void*       C;
  float*      out0;      // CW4 row-0 destination
  long long   aBS, bBS, cBS, auxBS;  // per-batch strides in ELEMENTS
  int Ktot, Mrows, ldc;
  int cin, logW, wpad, poff;
  float scale;
};

#define GLDS16(g, l)                                                        \
  __builtin_amdgcn_global_load_lds(                                         \
      (const void __attribute__((address_space(1)))*)(g),                   \
      (void __attribute__((address_space(3)))*)(l), 16, 0, 0)

// ---------------------------------------------------------------------------
// 8-phase-style deep-pipelined GEMM (T2+T3+T4+T5), BM=128 BN=256 BK=64,
// 8 waves (2M x 4N), triple-buffered LDS (no consumed-region races),
// counted vmcnt(6) (6 global_load_lds per K-tile; never drains in steady
// state). N must be exactly 256; M multiple of 128. NT = Ktot/64 >= 2.
// ---------------------------------------------------------------------------
template <int AMODE, int CW, bool RELU>
__global__ __launch_bounds__(512, 2) void k_gemm8(GP gp) {
  const int tid = threadIdx.x;
  const int l = tid & 63, w = tid >> 6;
  const int b = blockIdx.z;
  const int m0 = blockIdx.x * 128;
  const int wm = w >> 2, wn = w & 3;

  __shared__ __align__(16) u16 sm[3][24576];  // per buf: A[128*64] | B[256*64]

  f32x4 acc[4][4];
#pragma unroll
  for (int i = 0; i < 4; ++i)
#pragma unroll
    for (int j = 0; j < 4; ++j) acc[i][j] = (f32x4){0.f, 0.f, 0.f, 0.f};

  const u16* Ab = gp.A + (size_t)b * gp.aBS;
  const u16* Bb = gp.B + (size_t)b * gp.bBS;
  // source chunk swizzle: LDS slot cc of row r holds global chunk cc^(r&7)
  const int scoff = (((tid & 7) ^ ((tid >> 3) & 7)) << 3);

  const u16* aP[2];
  const u16* bP[4];
#pragma unroll
  for (int i = 0; i < 2; ++i) {
    const int p = m0 + i * 64 + (tid >> 3);
    if (AMODE == 0) {
      const int pc = p < gp.Mrows ? p : gp.Mrows - 1;
      aP[i] = Ab + (size_t)pc * gp.Ktot + scoff;
    } else {
      const int y = p >> gp.logW, x = p & ((1 << gp.logW) - 1);
      aP[i] = Ab + (size_t)((y + gp.poff) * gp.wpad + (x + gp.poff)) * gp.cin +
              scoff;
    }
  }
#pragma unroll
  for (int i = 0; i < 4; ++i)
    bP[i] = Bb + (size_t)(i * 64 + (tid >> 3)) * gp.Ktot + scoff;

  const int NT = gp.Ktot >> 6;
  int kcS = 0, tapS = 0, dxS = 0, ktS = 0;

  auto adv = [&](int& kA, int& kB) {
    kB = ktS << 6;
    if (AMODE == 0) {
      kA = ktS << 6;
    } else {
      kA = tapS * gp.cin + kcS;
      kcS += 64;
      if (kcS == gp.cin) {
        kcS = 0; ++dxS; ++tapS;
        if (dxS == 3) { dxS = 0; tapS += gp.wpad - 3; }
      }
    }
    ++ktS;
  };

  // ---- prologue: stage tiles 0,1 into bufs 0,1 ----
#pragma unroll
  for (int pt = 0; pt < 2; ++pt) {
    int kA, kB;
    adv(kA, kB);
    u16* sA = &sm[pt][0] + (w << 9);
    u16* sB = &sm[pt][8192] + (w << 9);
    GLDS16(aP[0] + kA, sA);
    GLDS16(aP[1] + kA, sA + 4096);
    GLDS16(bP[0] + kB, sB);
    GLDS16(bP[1] + kB, sB + 4096);
    GLDS16(bP[2] + kB, sB + 8192);
    GLDS16(bP[3] + kB, sB + 12288);
  }
  asm volatile("s_waitcnt vmcnt(6)" ::: "memory");
  __builtin_amdgcn_s_barrier();

  const int lr = l & 15, lc = l >> 4;
  int bufC = 0, bufS = 2;

  for (int t = 0; t < NT; ++t) {
    const u16* sAc = &sm[bufC][0];
    const u16* sBc = &sm[bufC][8192];
    const bool sOK = (t + 2 < NT);
    int kAs = 0, kBs = 0;
    if (sOK) adv(kAs, kBs);
    u16* sAs = &sm[bufS][0] + (w << 9);
    u16* sBs = &sm[bufS][8192] + (w << 9);

    bf16x8 bv[4][2];  // held across both phases
    // -------- phase 0: mi 0..1 x all ni --------
    {
      bf16x8 av[2][2];
#pragma unroll
      for (int mi = 0; mi < 2; ++mi) {
        const int row = wm * 64 + mi * 16 + lr;
#pragma unroll
        for (int ks = 0; ks < 2; ++ks) {
          const int cc = ks * 4 + lc;
          av[mi][ks] =
              *(const bf16x8*)(sAc + row * 64 + ((cc ^ (row & 7)) << 3));
        }
      }
#pragma unroll
      for (int ni = 0; ni < 4; ++ni) {
        const int row = wn * 64 + ni * 16 + lr;
#pragma unroll
        for (int ks = 0; ks < 2; ++ks) {
          const int cc = ks * 4 + lc;
          bv[ni][ks] =
              *(const bf16x8*)(sBc + row * 64 + ((cc ^ (row & 7)) << 3));
        }
      }
      if (sOK) {
        GLDS16(aP[0] + kAs, sAs);
        GLDS16(aP[1] + kAs, sAs + 4096);
        GLDS16(bP[0] + kBs, sBs);
      }
      __builtin_amdgcn_s_barrier();
      asm volatile("s_waitcnt lgkmcnt(0)" ::: "memory");
      __builtin_amdgcn_sched_barrier(0);
      __builtin_amdgcn_s_setprio(1);
#pragma unroll
      for (int ks = 0; ks < 2; ++ks)
#pragma unroll
        for (int mi = 0; mi < 2; ++mi)
#pragma unroll
          for (int ni = 0; ni < 4; ++ni)
            acc[mi][ni] = __builtin_amdgcn_mfma_f32_16x16x32_bf16(
                av[mi][ks], bv[ni][ks], acc[mi][ni], 0, 0, 0);
      __builtin_amdgcn_sched_barrier(0);
      __builtin_amdgcn_s_setprio(0);
    }
    __builtin_amdgcn_s_barrier();
    // -------- phase 1: mi 2..3 x all ni (bv reused) --------
    {
      bf16x8 av[2][2];
#pragma unroll
      for (int mi = 0; mi < 2; ++mi) {
        const int row = wm * 64 + (mi + 2) * 16 + lr;
#pragma unroll
        for (int ks = 0; ks < 2; ++ks) {
          const int cc = ks * 4 + lc;
          av[mi][ks] =
              *(const bf16x8*)(sAc + row * 64 + ((cc ^ (row & 7)) << 3));
        }
      }
      if (sOK) {
        GLDS16(bP[1] + kBs, sBs + 4096);
        GLDS16(bP[2] + kBs, sBs + 8192);
        GLDS16(bP[3] + kBs, sBs + 12288);
      }
      __builtin_amdgcn_s_barrier();
      asm volatile("s_waitcnt lgkmcnt(0)" ::: "memory");
      __builtin_amdgcn_sched_barrier(0);
      __builtin_amdgcn_s_setprio(1);
#pragma unroll
      for (int ks = 0; ks < 2; ++ks)
#pragma unroll
        for (int mi = 0; mi < 2; ++mi)
#pragma unroll
          for (int ni = 0; ni < 4; ++ni)
            acc[mi + 2][ni] = __builtin_amdgcn_mfma_f32_16x16x32_bf16(
                av[mi][ks], bv[ni][ks], acc[mi + 2][ni], 0, 0, 0);
      __builtin_amdgcn_sched_barrier(0);
      __builtin_amdgcn_s_setprio(0);
    }
    // tile boundary: next tile's data must be landed before its ds_reads
    if (t + 1 < NT) {
      if (t + 2 < NT)
        asm volatile("s_waitcnt vmcnt(6)" ::: "memory");
      else
        asm volatile("s_waitcnt vmcnt(0)" ::: "memory");
      __builtin_amdgcn_s_barrier();
    }
    bufC = bufC == 2 ? 0 : bufC + 1;
    bufS = bufS == 2 ? 0 : bufS + 1;
  }

  // ------------------------- epilogue ---------------------------
#pragma unroll
  for (int mi = 0; mi < 4; ++mi) {
#pragma unroll
    for (int ni = 0; ni < 4; ++ni) {
      const int ncol = wn * 64 + ni * 16 + lr;
      const int mbase = m0 + wm * 64 + mi * 16 + lc * 4;
      const float bv_ = gp.bias ? gp.bias[ncol] : 0.f;
      if constexpr (CW == 0) {
#pragma unroll
        for (int r = 0; r < 4; ++r) {
          float v = acc[mi][ni][r] + bv_;
          if (RELU) v = fmaxf(v, 0.f);
          ((u16*)gp.C)[(size_t)b * gp.cBS + (size_t)(mbase + r) * 256 + ncol] =
              f2b(v);
        }
      } else if constexpr (CW == 1) {
#pragma unroll
        for (int r = 0; r < 4; ++r) {
          float v = acc[mi][ni][r] + bv_;
          if (RELU) v = fmaxf(v, 0.f);
          const int mrow = mbase + r;
          const int y = mrow >> 6, x = mrow & 63;
          ((u16*)gp.C)[(size_t)b * gp.cBS +
                       (size_t)((y + 1) * 66 + x + 1) * 256 + ncol] = f2b(v);
        }
      } else if constexpr (CW == 2) {
#pragma unroll
        for (int r = 0; r < 4; ++r) {
          const int mrow = mbase + r;
          const float s =
              b2f(((const u16*)gp.aux)[(size_t)b * gp.auxBS +
                                       (size_t)mrow * 256 + ncol]);
          float v = acc[mi][ni][r] + bv_ + s;
          v = fmaxf(v, 0.f);
          ((float*)gp.C)[(size_t)b * gp.cBS + (size_t)mrow * 256 + ncol] = v;
        }
      } else if constexpr (CW == 6) {
        float* Cf =
            (float*)gp.C + (size_t)b * gp.cBS + (size_t)ncol * 4096 + mbase;
        const float* mid = (const float*)gp.aux + (size_t)b * gp.auxBS;
        f32x4 o;
#pragma unroll
        for (int r = 0; r < 4; ++r) {
          float v = acc[mi][ni][r] + bv_;
          v = fmaxf(v, 0.f);
          o[r] = v + mid[(size_t)(mbase + r) * 256 + ncol];
        }
        *(f32x4*)Cf = o;
      }
    }
  }
}

// ---------------------------------------------------------------------------
// Original 128x128 4-wave GEMM (kept for small-M / small-K ops).
// ---------------------------------------------------------------------------
template <int AMODE, int CW, bool RELU>
__global__ __launch_bounds__(256, 2) void k_gemm(GP gp) {
  const int tid = threadIdx.x;
  const int l = tid & 63, w = tid >> 6;
  const int b = blockIdx.z;
  const int m0 = blockIdx.x * 128, n0 = blockIdx.y * 128;
  const int wm = w >> 1, wn = w & 1;

  __shared__ __align__(16) u16 smA[128 * 64];
  __shared__ __align__(16) u16 smB[128 * 64];

  f32x4 acc[4][4];
#pragma unroll
  for (int i = 0; i < 4; ++i)
#pragma unroll
    for (int j = 0; j < 4; ++j) acc[i][j] = (f32x4){0.f, 0.f, 0.f, 0.f};

  const u16* Ab = gp.A + (size_t)b * gp.aBS;
  const u16* Bb = gp.B + (size_t)b * gp.bBS;

  const int scoff = (((l & 7) ^ (l >> 3)) << 3);

  const u16* aRow[4];
  const u16* bRow[4];
  u16* ldsA[4];
  u16* ldsB[4];
#pragma unroll
  for (int i = 0; i < 4; ++i) {
    const int r = w * 32 + i * 8 + (l >> 3);
    bRow[i] = Bb + (size_t)(n0 + r) * gp.Ktot + scoff;
    const int p = m0 + r;
    if (AMODE == 0) {
      const int pc = p < gp.Mrows ? p : gp.Mrows - 1;
      aRow[i] = Ab + (size_t)pc * gp.Ktot + scoff;
    } else {
      const int y = p >> gp.logW, x = p & ((1 << gp.logW) - 1);
      const int icoord = (y + gp.poff) * gp.wpad + (x + gp.poff);
      aRow[i] = Ab + (size_t)icoord * gp.cin + scoff;
    }
    ldsA[i] = smA + (w * 32 + i * 8) * 64;
    ldsB[i] = smB + (w * 32 + i * 8) * 64;
  }

  const int ktiles = gp.Ktot >> 6;
  int tap_off = 0, dx = 0, kc = 0;

  for (int kt = 0; kt < ktiles; ++kt) {
    int koffA;
    if (AMODE == 0)
      koffA = kt << 6;
    else
      koffA = tap_off * gp.cin + kc;
    const int koffB = kt << 6;
#pragma unroll
    for (int i = 0; i < 4; ++i) GLDS16(aRow[i] + koffA, ldsA[i]);
#pragma unroll
    for (int i = 0; i < 4; ++i) GLDS16(bRow[i] + koffB, ldsB[i]);

    if (AMODE == 1) {
      kc += 64;
      if (kc == gp.cin) {
        kc = 0;
        ++dx;
        ++tap_off;
        if (dx == 3) { dx = 0; tap_off += gp.wpad - 3; }
      }
    }

    __syncthreads();
#pragma unroll
    for (int ks = 0; ks < 2; ++ks) {
      bf16x8 av[4], bv[4];
      const int cc = (ks << 2) + (l >> 4);
#pragma unroll
      for (int mi = 0; mi < 4; ++mi) {
        const int row = wm * 64 + mi * 16 + (l & 15);
        av[mi] = *(const bf16x8*)((const char*)smA + (row << 7) +
                                  ((cc ^ (row & 7)) << 4));
      }
#pragma unroll
      for (int ni = 0; ni < 4; ++ni) {
        const int row = wn * 64 + ni * 16 + (l & 15);
        bv[ni] = *(const bf16x8*)((const char*)smB + (row << 7) +
                                  ((cc ^ (row & 7)) << 4));
      }
#pragma unroll
      for (int mi = 0; mi < 4; ++mi)
#pragma unroll
        for (int ni = 0; ni < 4; ++ni)
          acc[mi][ni] = __builtin_amdgcn_mfma_f32_16x16x32_bf16(
              av[mi], bv[ni], acc[mi][ni], 0, 0, 0);
    }
    __syncthreads();
  }

#pragma unroll
  for (int mi = 0; mi < 4; ++mi) {
#pragma unroll
    for (int ni = 0; ni < 4; ++ni) {
      const int ncol = n0 + wn * 64 + ni * 16 + (l & 15);
      const int mbase = m0 + wm * 64 + mi * 16 + ((l >> 4) << 2);
      const float bv_ = gp.bias ? gp.bias[ncol] : 0.f;

      if constexpr (CW == 3) {
        u16* Cu = (u16*)gp.C + (size_t)b * gp.cBS + (size_t)ncol * 4096 + mbase;
        u16x4 pk;
#pragma unroll
        for (int r = 0; r < 4; ++r) pk[r] = f2b(acc[mi][ni][r] + bv_);
        *(u16x4*)Cu = pk;
      } else if constexpr (CW == 7) {
        // fused key/value epilogue: gp.C = KT base; V = KT + 8388608 elems
        u16* base = (u16*)gp.C;
        if (ncol < 256) {
#pragma unroll
          for (int r = 0; r < 4; ++r)
            base[(size_t)b * 1048576 + (size_t)(mbase + r) * 256 + ncol] =
                f2b(acc[mi][ni][r] + bv_);
        } else {
          u16x4 pk;
#pragma unroll
          for (int r = 0; r < 4; ++r) pk[r] = f2b(acc[mi][ni][r] + bv_);
          *(u16x4*)(base + 8388608 + (size_t)b * 1048576 +
                    (size_t)(ncol - 256) * 4096 + mbase) = pk;
        }
      } else if constexpr (CW == 6) {
        float* Cf = (float*)gp.C + (size_t)b * gp.cBS + (size_t)ncol * 4096 + mbase;
        const float* mid = (const float*)gp.aux + (size_t)b * gp.auxBS;
        f32x4 o;
#pragma unroll
        for (int r = 0; r < 4; ++r) {
          float v = acc[mi][ni][r] + bv_;
          v = v > 0.f ? v : 0.f;
          o[r] = v + mid[(size_t)(mbase + r) * 256 + ncol];
        }
        *(f32x4*)Cf = o;
      } else {
#pragma unroll
        for (int reg = 0; reg < 4; ++reg) {
          const int mrow = mbase + reg;
          if (mrow >= gp.Mrows) continue;
          float v = acc[mi][ni][reg] * gp.scale + bv_;
          if (RELU) v = v > 0.f ? v : 0.f;
          if constexpr (CW == 0) {
            ((u16*)gp.C)[(size_t)b * gp.cBS + (size_t)mrow * gp.ldc + ncol] =
                f2b(v);
          } else if constexpr (CW == 2) {
            const float s =
                b2f(((const u16*)gp.aux)[(size_t)b * gp.auxBS +
                                         (size_t)mrow * 256 + ncol]);
            float v2 = v + s;
            v2 = v2 > 0.f ? v2 : 0.f;
            ((float*)gp.C)[(size_t)b * gp.cBS + (size_t)mrow * 256 + ncol] = v2;
          } else if constexpr (CW == 4) {
            if (mrow == 0) {
              gp.out0[(size_t)b * 256 + ncol] = v;
            } else {
              const int p = mrow - 1, y = p >> 5, x = p & 31;
              ((u16*)gp.C)[(size_t)b * gp.cBS +
                           (size_t)((y + 1) * 34 + (x + 1)) * 256 + ncol] =
                  f2b(v);
            }
          } else if constexpr (CW == 5) {
            ((float*)gp.C)[(size_t)b * gp.cBS + (size_t)mrow * 256 + ncol] = v;
          }
        }
      }
    }
  }
}

// --------------------------- prep / misc kernels ---------------------------

__global__ __launch_bounds__(256) void k_prep_x(const float* __restrict__ x,
                                                u16* __restrict__ o) {
  __shared__ float t[32][65];
  const int b = blockIdx.z, c0 = blockIdx.y << 5, y = blockIdx.x;
  const float* src = x + ((size_t)b * 1280 + c0) * 4096 + (size_t)y * 64;
#pragma unroll
  for (int i = 0; i < 8; ++i) {
    const int idx = threadIdx.x + (i << 8);
    const int c = idx >> 6, xx = idx & 63;
    t[c][xx] = src[(size_t)c * 4096 + xx];
  }
  __syncthreads();
  u16* dst = o + ((size_t)b * 4356 + (size_t)(y + 1) * 66 + 1) * 1280 + c0;
#pragma unroll
  for (int i = 0; i < 8; ++i) {
    const int idx = threadIdx.x + (i << 8);
    const int xx = idx >> 5, c = idx & 31;
    dst[(size_t)xx * 1280 + c] = f2b(t[c][xx]);
  }
}

// zero the 1-pixel border ring of a PxP padded NHWC bf16 buffer (8 batches)
__global__ __launch_bounds__(256) void k_zero_border(u16* __restrict__ p,
                                                     int P, int C) {
  const int per_img = (4 * P - 4) * C;
  const int total = 8 * per_img;
  for (int idx = blockIdx.x * 256 + threadIdx.x; idx < total;
       idx += gridDim.x * 256) {
    const int b = idx / per_img;
    const int r = idx % per_img;
    const int pix = r / C, c = r % C;
    int y, x;
    const int Pm = P - 1;
    if (pix < P) { y = 0; x = pix; }
    else if (pix < 2 * P) { y = Pm; x = pix - P; }
    else if (pix < 3 * P - 2) { y = pix - 2 * P + 1; x = 0; }
    else { y = pix - (3 * P - 2) + 1; x = Pm; }
    p[((size_t)b * P * P + (size_t)y * P + x) * C + c] = 0;
  }
}

__global__ __launch_bounds__(256) void k_prep_w3(const float* __restrict__ w,
                                                 u16* __restrict__ o, int cin,
                                                 int n) {
  for (int i = blockIdx.x * 256 + threadIdx.x; i < n; i += gridDim.x * 256) {
    const int ci = i % cin;
    const int r = i / cin;
    const int t = r % 9;
    const int co = r / 9;
    o[i] = f2b(w[((size_t)co * cin + ci) * 9 + t]);
  }
}

__global__ __launch_bounds__(256) void k_f2b(const float* __restrict__ x,
                                             u16* __restrict__ o, int n) {
  for (int i = blockIdx.x * 256 + threadIdx.x; i < n; i += gridDim.x * 256)
    o[i] = f2b(x[i]);
}

__global__ __launch_bounds__(256) void k_gn_stats(const float* __restrict__ x,
                                                  float* __restrict__ st) {
  const int b = blockIdx.y;
  const f32x4* xb = (const f32x4*)(x + (size_t)b * 1048576);
  float s = 0.f, s2 = 0.f;
  for (int i = blockIdx.x * 256 + threadIdx.x; i < 262144;
       i += gridDim.x * 256) {
    const f32x4 v = xb[i];
    s += v[0] + v[1] + v[2] + v[3];
    s2 += v[0] * v[0] + v[1] * v[1] + v[2] * v[2] + v[3] * v[3];
  }
#pragma unroll
  for (int o = 32; o; o >>= 1) {
    s += __shfl_down(s, o);
    s2 += __shfl_down(s2, o);
  }
  __shared__ float ls[4], ls2[4];
  const int w = threadIdx.x >> 6;
  if ((threadIdx.x & 63) == 0) { ls[w] = s; ls2[w] = s2; }
  __syncthreads();
  if (threadIdx.x == 0) {
    atomicAdd(&st[b * 2], ls[0] + ls[1] + ls[2] + ls[3]);
    atomicAdd(&st[b * 2 + 1], ls2[0] + ls2[1] + ls2[2] + ls2[3]);
  }
}

template <bool PAD>
__global__ __launch_bounds__(256) void k_gn_norm(const float* __restrict__ x,
                                                 const float* __restrict__ st,
                                                 const float* __restrict__ g,
                                                 const float* __restrict__ bb,
                                                 u16* __restrict__ o) {
  const int b = blockIdx.y;
  const float mu = st[b * 2] * (1.f / 1048576.f);
  const float var = st[b * 2 + 1] * (1.f / 1048576.f) - mu * mu;
  const float rs = rsqrtf(var + 1e-6f);
  const int i4 = blockIdx.x * 256 + threadIdx.x;
  const f32x4 v = ((const f32x4*)(x + (size_t)b * 1048576))[i4];
  const int flat = i4 << 2;
  const int c = flat & 255;
  const int p = flat >> 8;
  const f32x4 gv = *(const f32x4*)(g + c);
  const f32x4 bv = *(const f32x4*)(bb + c);
  u16x4 r;
#pragma unroll
  for (int k = 0; k < 4; ++k) r[k] = f2b((v[k] - mu) * rs * gv[k] + bv[k]);
  size_t oidx;
  if (PAD) {
    const int y = p >> 6, xx = p & 63;
    oidx = ((size_t)b * 4356 + (size_t)(y + 1) * 66 + xx + 1) * 256 + c;
  } else {
    oidx = ((size_t)b * 4096 + p) * 256 + c;
  }
  *(u16x4*)(o + oidx) = r;
}

__global__ __launch_bounds__(256) void k_softmax(u16* __restrict__ s) {
  const size_t row = blockIdx.x;
  u16* p = s + row * 4096;
  const int t = threadIdx.x;
  const short8 r0 = ((const short8*)p)[t];
  const short8 r1 = ((const short8*)p)[t + 256];
  float v[16];
#pragma unroll
  for (int i = 0; i < 8; ++i) {
    v[i] = b2f((u16)r0[i]);
    v[8 + i] = b2f((u16)r1[i]);
  }
  float m = v[0];
#pragma unroll
  for (int i = 1; i < 16; ++i) m = fmaxf(m, v[i]);
#pragma unroll
  for (int o = 32; o; o >>= 1) m = fmaxf(m, __shfl_xor(m, o));
  __shared__ float lm[4], lsum[4];
  const int w = t >> 6;
  if ((t & 63) == 0) lm[w] = m;
  __syncthreads();
  m = fmaxf(fmaxf(lm[0], lm[1]), fmaxf(lm[2], lm[3]));
  float sum = 0.f;
#pragma unroll
  for (int i = 0; i < 16; ++i) {
    v[i] = __expf(v[i] - m);
    sum += v[i];
  }
#pragma unroll
  for (int o = 32; o; o >>= 1) sum += __shfl_xor(sum, o);
  if ((t & 63) == 0) lsum[w] = sum;
  __syncthreads();
  sum = lsum[0] + lsum[1] + lsum[2] + lsum[3];
  const float inv = 1.f / sum;
  short8 o0, o1;
#pragma unroll
  for (int i = 0; i < 8; ++i) {
    o0[i] = (short)f2b(v[i] * inv);
    o1[i] = (short)f2b(v[8 + i] * inv);
  }
  ((short8*)p)[t] = o0;
  ((short8*)p)[t + 256] = o1;
}

__global__ __launch_bounds__(256) void k_resize_add(const float* __restrict__ d0,
                                                    const float* __restrict__ F,
                                                    float* __restrict__ mid) {
  const int i4 = blockIdx.x * 256 + threadIdx.x;
  const int flat = i4 << 2;
  const int c = flat & 255;
  const int p = (flat >> 8) & 4095;
  const int b = flat >> 20;
  const int y = p >> 6, x = p & 63;
  const float fy = y * (31.f / 63.f);
  const int y0 = (int)fy;
  const float wy = fy - y0;
  const int y1 = y0 + 1 > 31 ? 31 : y0 + 1;
  const float fx = x * (31.f / 63.f);
  const int x0 = (int)fx;
  const float wx = fx - x0;
  const int x1 = x0 + 1 > 31 ? 31 : x0 + 1;
  const float* db = d0 + (size_t)b * 262144;
  const f32x4 a = *(const f32x4*)(db + ((size_t)(y0 * 32 + x0) << 8) + c);
  const f32x4 bq = *(const f32x4*)(db + ((size_t)(y0 * 32 + x1) << 8) + c);
  const f32x4 cq = *(const f32x4*)(db + ((size_t)(y1 * 32 + x0) << 8) + c);
  const f32x4 dq = *(const f32x4*)(db + ((size_t)(y1 * 32 + x1) << 8) + c);
  f32x4 r = (a * (1.f - wx) + bq * wx) * (1.f - wy) +
            (cq * (1.f - wx) + dq * wx) * wy;
  r += *(const f32x4*)(F + (size_t)flat);
  *(f32x4*)(mid + (size_t)flat) = r;
}

// ---------------------------------------------------------------------------

extern "C" void kernel_launch(void* const* d_in, const int* in_sizes, int n_in,
                              void* d_out, int out_size, void* d_ws,
                              size_t ws_size, hipStream_t stream) {
  (void)in_sizes; (void)n_in; (void)out_size;

  const float* q   = (const float*)d_in[0];
  const float* xdc = (const float*)d_in[1];
  const float* w1  = (const float*)d_in[2];
  const float* b1  = (const float*)d_in[3];
  const float* w2  = (const float*)d_in[4];
  const float* b2  = (const float*)d_in[5];
  const float* wsc = (const float*)d_in[6];
  const float* bsc = (const float*)d_in[7];
  const float* lng = (const float*)d_in[8];
  const float* lnb = (const float*)d_in[9];
  const float* wk  = (const float*)d_in[10];
  const float* bk  = (const float*)d_in[11];
  const float* wv  = (const float*)d_in[12];
  const float* bv  = (const float*)d_in[13];
  const float* wd0 = (const float*)d_in[14];
  const float* bd0 = (const float*)d_in[15];
  const float* wd1 = (const float*)d_in[16];
  const float* bd1 = (const float*)d_in[17];

  char* ws = (char*)d_ws;
  size_t cur = 0;
  auto alloc = [&](size_t sz) {
    char* p = ws + cur;
    cur += sz;
    return p;
  };
  u16* XPAD = (u16*)alloc(89194496);   // 8*66*66*1280 bf16; reused for scores
  u16* W1R  = (u16*)alloc(5898240);    // 256*9*1280
  u16* W2R  = (u16*)alloc(1179648);    // 256*9*256
  u16* WSR  = (u16*)alloc(655360);     // 256*1280
  u16* WKV  = (u16*)alloc(262144);     // 512*256 (key || value weights)
  float* BKV = (float*)alloc(2048);    // 512 bias (bk || bv)
  u16* WD0R = (u16*)alloc(1179648);
  u16* WD1R = (u16*)alloc(1179648);
  u16* SB   = (u16*)alloc(16777216);   // shortcut, NHWC bf16
  u16* H1   = (u16*)alloc(17842176);   // conv1 out, padded NHWC bf16
  float* F  = (float*)alloc(33554432); // feat_diff NHWC fp32
  u16* FLN  = (u16*)alloc(16777216);   // gn1 out NHWC bf16
  u16* KT   = (u16*)alloc(16777216);   // key, [pixel][d]
  u16* V    = (u16*)alloc(16777216);   // value, [f][pixel] (MUST follow KT)
  u16* QB   = (u16*)alloc(4198400);    // query bf16 [1025][256]
  u16* OCP  = (u16*)alloc(4734976);    // attn spatial out, 34x34 padded NHWC
  float* D0O = (float*)alloc(8388608); // dh0 out NHWC fp32 (32x32)
  float* MID = (float*)alloc(33554432);// out_p mid NHWC fp32
  u16* G2   = (u16*)alloc(17842176);   // gn2 out, padded NHWC bf16
  float* ST = (float*)alloc(256);      // [0:16) gn1, [16:32) gn2
  u16* SCORES = XPAD;                  // alias (X_pad dead after conv1/shortcut)
  (void)V;

  if (ws_size < cur) return;

  float* out0 = (float*)d_out;           // (8,1,256)
  float* out1 = (float*)d_out + 2048;    // (8,256,64,64) NCHW

  hipMemsetAsync(ST, 0, 256, stream);
  hipMemcpyAsync(BKV, bk, 1024, hipMemcpyDeviceToDevice, stream);
  hipMemcpyAsync(BKV + 256, bv, 1024, hipMemcpyDeviceToDevice, stream);

  // zero only the padded borders (replaces 130 MB of memsets)
  k_zero_border<<<2048, 256, 0, stream>>>(XPAD, 66, 1280);
  k_zero_border<<<1024, 256, 0, stream>>>(H1, 66, 256);
  k_zero_border<<<1024, 256, 0, stream>>>(G2, 66, 256);
  k_zero_border<<<512, 256, 0, stream>>>(OCP, 34, 256);

  k_prep_x<<<dim3(64, 40, 8), 256, 0, stream>>>(xdc, XPAD);
  k_prep_w3<<<2048, 256, 0, stream>>>(w1, W1R, 1280, 2949120);
  k_prep_w3<<<1024, 256, 0, stream>>>(w2, W2R, 256, 589824);
  k_prep_w3<<<1024, 256, 0, stream>>>(wd0, WD0R, 256, 589824);
  k_prep_w3<<<1024, 256, 0, stream>>>(wd1, WD1R, 256, 589824);
  k_f2b<<<512, 256, 0, stream>>>(wsc, WSR, 327680);
  k_f2b<<<128, 256, 0, stream>>>(wk, WKV, 65536);
  k_f2b<<<128, 256, 0, stream>>>(wv, WKV + 65536, 65536);
  k_f2b<<<2048, 256, 0, stream>>>(q, QB, 2099200);

  const dim3 g8(32, 1, 8);
  // shortcut 1x1: X_pad(interior) x WSR -> SB (bf16, +bias, no relu)
  {
    GP g{};
    g.A = XPAD; g.B = WSR; g.bias = bsc; g.C = SB;
    g.aBS = 5575680; g.bBS = 0; g.cBS = 1048576;
    g.Ktot = 1280; g.Mrows = 4096; g.ldc = 256;
    g.cin = 1280; g.logW = 6; g.wpad = 66; g.poff = 1; g.scale = 1.f;
    k_gemm8<1, 0, false><<<g8, 512, 0, stream>>>(g);
  }
  // conv1 3x3: X_pad x W1R -> H1 (padded bf16, relu)
  {
    GP g{};
    g.A = XPAD; g.B = W1R; g.bias = b1; g.C = H1;
    g.aBS = 5575680; g.bBS = 0; g.cBS = 1115136;
    g.Ktot = 11520; g.Mrows = 4096; g.ldc = 256;
    g.cin = 1280; g.logW = 6; g.wpad = 66; g.poff = 0; g.scale = 1.f;
    k_gemm8<1, 1, true><<<g8, 512, 0, stream>>>(g);
  }
  // conv2 3x3: H1 x W2R (+bias +SB, relu) -> F fp32
  {
    GP g{};
    g.A = H1; g.B = W2R; g.bias = b2; g.C = F; g.aux = SB;
    g.aBS = 1115136; g.bBS = 0; g.cBS = 1048576; g.auxBS = 1048576;
    g.Ktot = 2304; g.Mrows = 4096; g.ldc = 256;
    g.cin = 256; g.logW = 6; g.wpad = 66; g.poff = 0; g.scale = 1.f;
    k_gemm8<1, 2, false><<<g8, 512, 0, stream>>>(g);
  }
  // gn1
  k_gn_stats<<<dim3(64, 8), 256, 0, stream>>>(F, ST);
  k_gn_norm<false><<<dim3(1024, 8), 256, 0, stream>>>(F, ST, lng, lnb, FLN);
  // fused key+value 1x1: FLN x WKV -> KT [pixel][256] and V [f][pixel]
  {
    GP g{};
    g.A = FLN; g.B = WKV; g.bias = BKV; g.C = KT;
    g.aBS = 1048576; g.bBS = 0; g.cBS = 0;
    g.Ktot = 256; g.Mrows = 4096; g.ldc = 256; g.scale = 1.f;
    k_gemm<0, 7, false><<<dim3(32, 4, 8), 256, 0, stream>>>(g);
  }
  // scores: QB x KT^T * (1/16) -> SCORES bf16 [1025][4096]
  {
    GP g{};
    g.A = QB; g.B = KT; g.bias = nullptr; g.C = SCORES;
    g.aBS = 262400; g.bBS = 1048576; g.cBS = 4198400;
    g.Ktot = 256; g.Mrows = 1025; g.ldc = 4096; g.scale = 0.0625f;
    k_gemm<0, 0, false><<<dim3(9, 32, 8), 256, 0, stream>>>(g);
  }
  k_softmax<<<8200, 256, 0, stream>>>(SCORES);
  // attn out: SCORES x V^T -> row0 to d_out, rows 1..1024 to OCP (34x34 pad)
  {
    GP g{};
    g.A = SCORES; g.B = V; g.bias = nullptr; g.C = OCP; g.out0 = out0;
    g.aBS = 4198400; g.bBS = 1048576; g.cBS = 295936;
    g.Ktot = 4096; g.Mrows = 1025; g.ldc = 256; g.scale = 1.f;
    k_gemm<0, 4, false><<<dim3(9, 2, 8), 256, 0, stream>>>(g);
  }
  // dh0 3x3 @32x32: OCP x WD0R (+bias, relu) -> D0O fp32
  {
    GP g{};
    g.A = OCP; g.B = WD0R; g.bias = bd0; g.C = D0O;
    g.aBS = 295936; g.bBS = 0; g.cBS = 262144;
    g.Ktot = 2304; g.Mrows = 1024; g.ldc = 256;
    g.cin = 256; g.logW = 5; g.wpad = 34; g.poff = 0; g.scale = 1.f;
    k_gemm<1, 5, true><<<dim3(8, 2, 8), 256, 0, stream>>>(g);
  }
  // bilinear upsample + add F -> MID
  k_resize_add<<<8192, 256, 0, stream>>>(D0O, F, MID);
  // gn2
  k_gn_stats<<<dim3(64, 8), 256, 0, stream>>>(MID, ST + 16);
  k_gn_norm<true><<<dim3(1024, 8), 256, 0, stream>>>(MID, ST + 16, lng, lnb, G2);
  // dh1 3x3: G2 x WD1R, relu(acc+bias)+MID -> out1 (NCHW fp32)
  {
    GP g{};
    g.A = G2; g.B = WD1R; g.bias = bd1; g.C = out1; g.aux = MID;
    g.aBS = 1115136; g.bBS = 0; g.cBS = 1048576; g.auxBS = 1048576;
    g.Ktot = 2304; g.Mrows = 4096; g.ldc = 256;
    g.cin = 256; g.logW = 6; g.wpad = 66; g.poff = 0; g.scale = 1.f;
    k_gemm8<1, 6, false><<<g8, 512, 0, stream>>>(g);
  }
}

// Round 4
// 724.198 us; speedup vs baseline: 1.0506x; 1.0270x over previous
//
#include <hip/hip_runtime.h>
#include <cstdint>
#include <cstddef>

typedef __attribute__((ext_vector_type(4))) float     f32x4;
typedef __attribute__((ext_vector_type(8))) __bf16    bf16x8;
typedef __attribute__((ext_vector_type(8))) short     short8;
typedef __attribute__((ext_vector_type(4))) unsigned short u16x4;
typedef unsigned short u16;

__device__ __forceinline__ float b2f(u16 u) {
  unsigned x = ((unsigned)u) << 16;
  float f;
  __builtin_memcpy(&f, &x, 4);
  return f;
}
__device__ __forceinline__ u16 f2b(float f) {
  unsigned u;
  __builtin_memcpy(&u, &f, 4);
  return (u16)((u + 0x7FFFu + ((u >> 16) & 1u)) >> 16);
}

struct GP {
  const u16*  A;
  const u16*  B;
  const float* bias;
  const void* aux;
  void*       C;
  float*      out0;
  long long   aBS, bBS, cBS, auxBS;
  int Ktot, Mrows, ldc;
  int cin, logW, wpad, poff;
  float scale;
};

#define GLDS16(g, l)                                                        \
  __builtin_amdgcn_global_load_lds(                                         \
      (const void __attribute__((address_space(1)))*)(g),                   \
      (void __attribute__((address_space(3)))*)(l), 16, 0, 0)

// ---------------------------------------------------------------------------
// 256x256 8-wave GEMM, per-wave 128x64, BK=64, split-K=2 (blockIdx.y),
// 4 quadrant-phases per K-tile, counted vmcnt(4), fp32 partial output.
// ---------------------------------------------------------------------------
struct G256 {
  const u16* A;
  const u16* B;
  float* P;
  long long aBS;
  int Ktot, cin, logW, wpad, poff;
};

__global__ __launch_bounds__(512, 2) void k_gemm256(G256 gp) {
  const int tid = threadIdx.x;
  const int l = tid & 63, w = tid >> 6;
  const int lr = l & 15, lc = l >> 4;
  const int mt = blockIdx.x, sp = blockIdx.y, b = blockIdx.z;
  const int m0 = mt << 8;
  const int wm = w >> 2, wn = w & 3;

  __shared__ __align__(16) u16 sm[2][32768];
  u16* smb = &sm[0][0];

  f32x4 acc[8][4];
#pragma unroll
  for (int i = 0; i < 8; ++i)
#pragma unroll
    for (int j = 0; j < 4; ++j) acc[i][j] = (f32x4){0.f, 0.f, 0.f, 0.f};

  const u16* Ab = gp.A + (size_t)b * gp.aBS;
  const int slot = l & 3;
  const u16* aS[2];
  const u16* bS[2];
#pragma unroll
  for (int j = 0; j < 2; ++j) {
    const int r = j * 128 + w * 16 + (l >> 2);
    const int p = m0 + r;
    const int y = p >> gp.logW, x = p & ((1 << gp.logW) - 1);
    const int sw = (slot ^ ((r >> 1) & 3)) << 3;
    aS[j] = Ab + (size_t)((y + gp.poff) * gp.wpad + (x + gp.poff)) * gp.cin + sw;
    bS[j] = gp.B + (size_t)r * gp.Ktot + sw;
  }
  auto dstA = [&](int buf, int ks, int j) -> u16* {
    return smb + buf * 32768 + ks * 8192 + (j * 128 + w * 16) * 32 + l * 8;
  };
  auto dstB = [&](int buf, int ks, int j) -> u16* {
    return smb + buf * 32768 + 16384 + ks * 8192 + (j * 128 + w * 16) * 32 + l * 8;
  };

  const int Thalf = (gp.Ktot >> 6) >> 1;
  const int kt0 = sp * Thalf;
  int off = kt0 << 6;
  int tap = off / gp.cin;
  int kcS = off - tap * gp.cin;
  int dxS = tap % 3;
  int tapS = (tap / 3) * gp.wpad + dxS;
  int ktS = kt0;

  auto adv = [&](int& kA, int& kB) {
    kB = ktS << 6;
    kA = tapS * gp.cin + kcS;
    kcS += 64;
    if (kcS == gp.cin) {
      kcS = 0; ++dxS; ++tapS;
      if (dxS == 3) { dxS = 0; tapS += gp.wpad - 3; }
    }
    ++ktS;
  };

  {
    int kA, kB;
    adv(kA, kB);
    GLDS16(aS[0] + kA, dstA(0, 0, 0));
    GLDS16(aS[1] + kA, dstA(0, 0, 1));
    GLDS16(bS[0] + kB, dstB(0, 0, 0));
    GLDS16(bS[1] + kB, dstB(0, 0, 1));
    GLDS16(aS[0] + kA + 32, dstA(0, 1, 0));
    GLDS16(aS[1] + kA + 32, dstA(0, 1, 1));
    GLDS16(bS[0] + kB + 32, dstB(0, 1, 0));
    GLDS16(bS[1] + kB + 32, dstB(0, 1, 1));
  }
  asm volatile("s_waitcnt vmcnt(4)" ::: "memory");
  __builtin_amdgcn_s_barrier();

  const int NT = Thalf;
  for (int t = 0; t < NT; ++t) {
    const int buf = t & 1;
    const char* base = (const char*)smb + buf * 65536;
    const bool pf = (t + 1 < NT);
    int kA = 0, kB = 0;
    if (pf) adv(kA, kB);

    bf16x8 av[4], bv[4];

    // ---- ph1: (mq=0, ks=0) ----
#pragma unroll
    for (int mi = 0; mi < 4; ++mi) {
      const int row = wm * 128 + mi * 16 + lr;
      av[mi] = *(const bf16x8*)(base + row * 64 + ((lc ^ ((row >> 1) & 3)) << 4));
    }
#pragma unroll
    for (int ni = 0; ni < 4; ++ni) {
      const int row = wn * 64 + ni * 16 + lr;
      bv[ni] = *(const bf16x8*)(base + 32768 + row * 64 +
                                ((lc ^ ((row >> 1) & 3)) << 4));
    }
    if (pf) {
      GLDS16(aS[0] + kA, dstA(buf ^ 1, 0, 0));
      GLDS16(aS[1] + kA, dstA(buf ^ 1, 0, 1));
    }
    __builtin_amdgcn_s_barrier();
    asm volatile("s_waitcnt lgkmcnt(0)" ::: "memory");
    __builtin_amdgcn_sched_barrier(0);
    __builtin_amdgcn_s_setprio(1);
#pragma unroll
    for (int mi = 0; mi < 4; ++mi)
#pragma unroll
      for (int ni = 0; ni < 4; ++ni)
        acc[mi][ni] = __builtin_amdgcn_mfma_f32_16x16x32_bf16(
            av[mi], bv[ni], acc[mi][ni], 0, 0, 0);
    __builtin_amdgcn_s_setprio(0);
    __builtin_amdgcn_sched_barrier(0);
    __builtin_amdgcn_s_barrier();

    // ---- ph2: (mq=1, ks=0), bv reused ----
#pragma unroll
    for (int mi = 0; mi < 4; ++mi) {
      const int row = wm * 128 + (4 + mi) * 16 + lr;
      av[mi] = *(const bf16x8*)(base + row * 64 + ((lc ^ ((row >> 1) & 3)) << 4));
    }
    if (pf) {
      GLDS16(bS[0] + kB, dstB(buf ^ 1, 0, 0));
      GLDS16(bS[1] + kB, dstB(buf ^ 1, 0, 1));
    }
    __builtin_amdgcn_s_barrier();
    asm volatile("s_waitcnt lgkmcnt(0)" ::: "memory");
    __builtin_amdgcn_sched_barrier(0);
    __builtin_amdgcn_s_setprio(1);
#pragma unroll
    for (int mi = 0; mi < 4; ++mi)
#pragma unroll
      for (int ni = 0; ni < 4; ++ni)
        acc[4 + mi][ni] = __builtin_amdgcn_mfma_f32_16x16x32_bf16(
            av[mi], bv[ni], acc[4 + mi][ni], 0, 0, 0);
    __builtin_amdgcn_s_setprio(0);
    __builtin_amdgcn_sched_barrier(0);
    if (pf)
      asm volatile("s_waitcnt vmcnt(4)" ::: "memory");
    else
      asm volatile("s_waitcnt vmcnt(0)" ::: "memory");
    __builtin_amdgcn_s_barrier();

    // ---- ph3: (mq=0, ks=1) ----
#pragma unroll
    for (int mi = 0; mi < 4; ++mi) {
      const int row = wm * 128 + mi * 16 + lr;
      av[mi] = *(const bf16x8*)(base + 16384 + row * 64 +
                                ((lc ^ ((row >> 1) & 3)) << 4));
    }
#pragma unroll
    for (int ni = 0; ni < 4; ++ni) {
      const int row = wn * 64 + ni * 16 + lr;
      bv[ni] = *(const bf16x8*)(base + 49152 + row * 64 +
                                ((lc ^ ((row >> 1) & 3)) << 4));
    }
    if (pf) {
      GLDS16(aS[0] + kA + 32, dstA(buf ^ 1, 1, 0));
      GLDS16(aS[1] + kA + 32, dstA(buf ^ 1, 1, 1));
    }
    __builtin_amdgcn_s_barrier();
    asm volatile("s_waitcnt lgkmcnt(0)" ::: "memory");
    __builtin_amdgcn_sched_barrier(0);
    __builtin_amdgcn_s_setprio(1);
#pragma unroll
    for (int mi = 0; mi < 4; ++mi)
#pragma unroll
      for (int ni = 0; ni < 4; ++ni)
        acc[mi][ni] = __builtin_amdgcn_mfma_f32_16x16x32_bf16(
            av[mi], bv[ni], acc[mi][ni], 0, 0, 0);
    __builtin_amdgcn_s_setprio(0);
    __builtin_amdgcn_sched_barrier(0);
    __builtin_amdgcn_s_barrier();

    // ---- ph4: (mq=1, ks=1), bv reused ----
#pragma unroll
    for (int mi = 0; mi < 4; ++mi) {
      const int row = wm * 128 + (4 + mi) * 16 + lr;
      av[mi] = *(const bf16x8*)(base + 16384 + row * 64 +
                                ((lc ^ ((row >> 1) & 3)) << 4));
    }
    if (pf) {
      GLDS16(bS[0] + kB + 32, dstB(buf ^ 1, 1, 0));
      GLDS16(bS[1] + kB + 32, dstB(buf ^ 1, 1, 1));
    }
    __builtin_amdgcn_s_barrier();
    asm volatile("s_waitcnt lgkmcnt(0)" ::: "memory");
    __builtin_amdgcn_sched_barrier(0);
    __builtin_amdgcn_s_setprio(1);
#pragma unroll
    for (int mi = 0; mi < 4; ++mi)
#pragma unroll
      for (int ni = 0; ni < 4; ++ni)
        acc[4 + mi][ni] = __builtin_amdgcn_mfma_f32_16x16x32_bf16(
            av[mi], bv[ni], acc[4 + mi][ni], 0, 0, 0);
    __builtin_amdgcn_s_setprio(0);
    __builtin_amdgcn_sched_barrier(0);
    if (pf) {
      asm volatile("s_waitcnt vmcnt(4)" ::: "memory");
      __builtin_amdgcn_s_barrier();
    }
  }

  float* P = gp.P + ((size_t)sp * 128 + b * 16 + mt) * 65536;
#pragma unroll
  for (int mi = 0; mi < 8; ++mi)
#pragma unroll
    for (int ni = 0; ni < 4; ++ni) {
      const int ncol = wn * 64 + ni * 16 + lr;
      const int mloc = wm * 128 + mi * 16 + lc * 4;
#pragma unroll
      for (int r = 0; r < 4; ++r)
        P[(size_t)(mloc + r) * 256 + ncol] = acc[mi][ni][r];
    }
}

// reduce conv1 partials: relu(p0+p1+bias) -> padded NHWC bf16 H1
__global__ __launch_bounds__(256) void k_reduceH1(const float* __restrict__ P,
                                                  const float* __restrict__ bias,
                                                  u16* __restrict__ o) {
  const int i4 = blockIdx.x * 256 + threadIdx.x;  // grid 8192 exact
  const int flat = i4 << 2;
  const int n0 = flat & 255;
  const int mloc = (flat >> 8) & 255;
  const int gm = flat >> 16;
  const f32x4 a = *(const f32x4*)(P + (size_t)gm * 65536 + mloc * 256 + n0);
  const f32x4 c = *(const f32x4*)(P + (size_t)(128 + gm) * 65536 + mloc * 256 + n0);
  const f32x4 bb = *(const f32x4*)(bias + n0);
  const int batch = gm >> 4;
  const int mg = (gm & 15) * 256 + mloc;
  const int y = mg >> 6, x = mg & 63;
  u16x4 r;
#pragma unroll
  for (int k = 0; k < 4; ++k) r[k] = f2b(fmaxf(a[k] + c[k] + bb[k], 0.f));
  *(u16x4*)(o + ((size_t)batch * 4356 + (size_t)(y + 1) * 66 + x + 1) * 256 + n0) = r;
}

// ---------------------------------------------------------------------------
// 128x256 8-wave pipelined GEMM (conv2/dh1/shortcut).
// ---------------------------------------------------------------------------
template <int AMODE, int CW, bool RELU>
__global__ __launch_bounds__(512, 2) void k_gemm8(GP gp) {
  const int tid = threadIdx.x;
  const int l = tid & 63, w = tid >> 6;
  const int b = blockIdx.z;
  const int m0 = blockIdx.x * 128;
  const int wm = w >> 2, wn = w & 3;

  __shared__ __align__(16) u16 sm[3][24576];

  f32x4 acc[4][4];
#pragma unroll
  for (int i = 0; i < 4; ++i)
#pragma unroll
    for (int j = 0; j < 4; ++j) acc[i][j] = (f32x4){0.f, 0.f, 0.f, 0.f};

  const u16* Ab = gp.A + (size_t)b * gp.aBS;
  const u16* Bb = gp.B + (size_t)b * gp.bBS;
  const int scoff = (((tid & 7) ^ ((tid >> 3) & 7)) << 3);

  const u16* aP[2];
  const u16* bP[4];
#pragma unroll
  for (int i = 0; i < 2; ++i) {
    const int p = m0 + i * 64 + (tid >> 3);
    if (AMODE == 0) {
      const int pc = p < gp.Mrows ? p : gp.Mrows - 1;
      aP[i] = Ab + (size_t)pc * gp.Ktot + scoff;
    } else {
      const int y = p >> gp.logW, x = p & ((1 << gp.logW) - 1);
      aP[i] = Ab + (size_t)((y + gp.poff) * gp.wpad + (x + gp.poff)) * gp.cin +
              scoff;
    }
  }
#pragma unroll
  for (int i = 0; i < 4; ++i)
    bP[i] = Bb + (size_t)(i * 64 + (tid >> 3)) * gp.Ktot + scoff;

  const int NT = gp.Ktot >> 6;
  int kcS = 0, tapS = 0, dxS = 0, ktS = 0;

  auto adv = [&](int& kA, int& kB) {
    kB = ktS << 6;
    if (AMODE == 0) {
      kA = ktS << 6;
    } else {
      kA = tapS * gp.cin + kcS;
      kcS += 64;
      if (kcS == gp.cin) {
        kcS = 0; ++dxS; ++tapS;
        if (dxS == 3) { dxS = 0; tapS += gp.wpad - 3; }
      }
    }
    ++ktS;
  };

#pragma unroll
  for (int pt = 0; pt < 2; ++pt) {
    int kA, kB;
    adv(kA, kB);
    u16* sA = &sm[pt][0] + (w << 9);
    u16* sB = &sm[pt][8192] + (w << 9);
    GLDS16(aP[0] + kA, sA);
    GLDS16(aP[1] + kA, sA + 4096);
    GLDS16(bP[0] + kB, sB);
    GLDS16(bP[1] + kB, sB + 4096);
    GLDS16(bP[2] + kB, sB + 8192);
    GLDS16(bP[3] + kB, sB + 12288);
  }
  asm volatile("s_waitcnt vmcnt(6)" ::: "memory");
  __builtin_amdgcn_s_barrier();

  const int lr = l & 15, lc = l >> 4;
  int bufC = 0, bufS = 2;

  for (int t = 0; t < NT; ++t) {
    const u16* sAc = &sm[bufC][0];
    const u16* sBc = &sm[bufC][8192];
    const bool sOK = (t + 2 < NT);
    int kAs = 0, kBs = 0;
    if (sOK) adv(kAs, kBs);
    u16* sAs = &sm[bufS][0] + (w << 9);
    u16* sBs = &sm[bufS][8192] + (w << 9);

    bf16x8 bv[4][2];
    {
      bf16x8 av[2][2];
#pragma unroll
      for (int mi = 0; mi < 2; ++mi) {
        const int row = wm * 64 + mi * 16 + lr;
#pragma unroll
        for (int ks = 0; ks < 2; ++ks) {
          const int cc = ks * 4 + lc;
          av[mi][ks] =
              *(const bf16x8*)(sAc + row * 64 + ((cc ^ (row & 7)) << 3));
        }
      }
#pragma unroll
      for (int ni = 0; ni < 4; ++ni) {
        const int row = wn * 64 + ni * 16 + lr;
#pragma unroll
        for (int ks = 0; ks < 2; ++ks) {
          const int cc = ks * 4 + lc;
          bv[ni][ks] =
              *(const bf16x8*)(sBc + row * 64 + ((cc ^ (row & 7)) << 3));
        }
      }
      if (sOK) {
        GLDS16(aP[0] + kAs, sAs);
        GLDS16(aP[1] + kAs, sAs + 4096);
        GLDS16(bP[0] + kBs, sBs);
      }
      __builtin_amdgcn_s_barrier();
      asm volatile("s_waitcnt lgkmcnt(0)" ::: "memory");
      __builtin_amdgcn_sched_barrier(0);
      __builtin_amdgcn_s_setprio(1);
#pragma unroll
      for (int ks = 0; ks < 2; ++ks)
#pragma unroll
        for (int mi = 0; mi < 2; ++mi)
#pragma unroll
          for (int ni = 0; ni < 4; ++ni)
            acc[mi][ni] = __builtin_amdgcn_mfma_f32_16x16x32_bf16(
                av[mi][ks], bv[ni][ks], acc[mi][ni], 0, 0, 0);
      __builtin_amdgcn_sched_barrier(0);
      __builtin_amdgcn_s_setprio(0);
    }
    __builtin_amdgcn_s_barrier();
    {
      bf16x8 av[2][2];
#pragma unroll
      for (int mi = 0; mi < 2; ++mi) {
        const int row = wm * 64 + (mi + 2) * 16 + lr;
#pragma unroll
        for (int ks = 0; ks < 2; ++ks) {
          const int cc = ks * 4 + lc;
          av[mi][ks] =
              *(const bf16x8*)(sAc + row * 64 + ((cc ^ (row & 7)) << 3));
        }
      }
      if (sOK) {
        GLDS16(bP[1] + kBs, sBs + 4096);
        GLDS16(bP[2] + kBs, sBs + 8192);
        GLDS16(bP[3] + kBs, sBs + 12288);
      }
      __builtin_amdgcn_s_barrier();
      asm volatile("s_waitcnt lgkmcnt(0)" ::: "memory");
      __builtin_amdgcn_sched_barrier(0);
      __builtin_amdgcn_s_setprio(1);
#pragma unroll
      for (int ks = 0; ks < 2; ++ks)
#pragma unroll
        for (int mi = 0; mi < 2; ++mi)
#pragma unroll
          for (int ni = 0; ni < 4; ++ni)
            acc[mi + 2][ni] = __builtin_amdgcn_mfma_f32_16x16x32_bf16(
                av[mi][ks], bv[ni][ks], acc[mi + 2][ni], 0, 0, 0);
      __builtin_amdgcn_sched_barrier(0);
      __builtin_amdgcn_s_setprio(0);
    }
    if (t + 1 < NT) {
      if (t + 2 < NT)
        asm volatile("s_waitcnt vmcnt(6)" ::: "memory");
      else
        asm volatile("s_waitcnt vmcnt(0)" ::: "memory");
      __builtin_amdgcn_s_barrier();
    }
    bufC = bufC == 2 ? 0 : bufC + 1;
    bufS = bufS == 2 ? 0 : bufS + 1;
  }

#pragma unroll
  for (int mi = 0; mi < 4; ++mi) {
#pragma unroll
    for (int ni = 0; ni < 4; ++ni) {
      const int ncol = wn * 64 + ni * 16 + lr;
      const int mbase = m0 + wm * 64 + mi * 16 + lc * 4;
      const float bv_ = gp.bias ? gp.bias[ncol] : 0.f;
      if constexpr (CW == 0) {
#pragma unroll
        for (int r = 0; r < 4; ++r) {
          float v = acc[mi][ni][r] + bv_;
          if (RELU) v = fmaxf(v, 0.f);
          ((u16*)gp.C)[(size_t)b * gp.cBS + (size_t)(mbase + r) * 256 + ncol] =
              f2b(v);
        }
      } else if constexpr (CW == 1) {
#pragma unroll
        for (int r = 0; r < 4; ++r) {
          float v = acc[mi][ni][r] + bv_;
          if (RELU) v = fmaxf(v, 0.f);
          const int mrow = mbase + r;
          const int y = mrow >> 6, x = mrow & 63;
          ((u16*)gp.C)[(size_t)b * gp.cBS +
                       (size_t)((y + 1) * 66 + x + 1) * 256 + ncol] = f2b(v);
        }
      } else if constexpr (CW == 2) {
#pragma unroll
        for (int r = 0; r < 4; ++r) {
          const int mrow = mbase + r;
          const float s =
              b2f(((const u16*)gp.aux)[(size_t)b * gp.auxBS +
                                       (size_t)mrow * 256 + ncol]);
          float v = acc[mi][ni][r] + bv_ + s;
          v = fmaxf(v, 0.f);
          ((float*)gp.C)[(size_t)b * gp.cBS + (size_t)mrow * 256 + ncol] = v;
        }
      } else if constexpr (CW == 6) {
        float* Cf =
            (float*)gp.C + (size_t)b * gp.cBS + (size_t)ncol * 4096 + mbase;
        const float* mid = (const float*)gp.aux + (size_t)b * gp.auxBS;
        f32x4 o;
#pragma unroll
        for (int r = 0; r < 4; ++r) {
          float v = acc[mi][ni][r] + bv_;
          v = fmaxf(v, 0.f);
          o[r] = v + mid[(size_t)(mbase + r) * 256 + ncol];
        }
        *(f32x4*)Cf = o;
      }
    }
  }
}

// ---------------------------------------------------------------------------
// Original 128x128 4-wave GEMM (small-M / small-K ops).
// ---------------------------------------------------------------------------
template <int AMODE, int CW, bool RELU>
__global__ __launch_bounds__(256, 2) void k_gemm(GP gp) {
  const int tid = threadIdx.x;
  const int l = tid & 63, w = tid >> 6;
  const int b = blockIdx.z;
  const int m0 = blockIdx.x * 128, n0 = blockIdx.y * 128;
  const int wm = w >> 1, wn = w & 1;

  __shared__ __align__(16) u16 smA[128 * 64];
  __shared__ __align__(16) u16 smB[128 * 64];

  f32x4 acc[4][4];
#pragma unroll
  for (int i = 0; i < 4; ++i)
#pragma unroll
    for (int j = 0; j < 4; ++j) acc[i][j] = (f32x4){0.f, 0.f, 0.f, 0.f};

  const u16* Ab = gp.A + (size_t)b * gp.aBS;
  const u16* Bb = gp.B + (size_t)b * gp.bBS;

  const int scoff = (((l & 7) ^ (l >> 3)) << 3);

  const u16* aRow[4];
  const u16* bRow[4];
  u16* ldsA[4];
  u16* ldsB[4];
#pragma unroll
  for (int i = 0; i < 4; ++i) {
    const int r = w * 32 + i * 8 + (l >> 3);
    bRow[i] = Bb + (size_t)(n0 + r) * gp.Ktot + scoff;
    const int p = m0 + r;
    if (AMODE == 0) {
      const int pc = p < gp.Mrows ? p : gp.Mrows - 1;
      aRow[i] = Ab + (size_t)pc * gp.Ktot + scoff;
    } else {
      const int y = p >> gp.logW, x = p & ((1 << gp.logW) - 1);
      const int icoord = (y + gp.poff) * gp.wpad + (x + gp.poff);
      aRow[i] = Ab + (size_t)icoord * gp.cin + scoff;
    }
    ldsA[i] = smA + (w * 32 + i * 8) * 64;
    ldsB[i] = smB + (w * 32 + i * 8) * 64;
  }

  const int ktiles = gp.Ktot >> 6;
  int tap_off = 0, dx = 0, kc = 0;

  for (int kt = 0; kt < ktiles; ++kt) {
    int koffA;
    if (AMODE == 0)
      koffA = kt << 6;
    else
      koffA = tap_off * gp.cin + kc;
    const int koffB = kt << 6;
#pragma unroll
    for (int i = 0; i < 4; ++i) GLDS16(aRow[i] + koffA, ldsA[i]);
#pragma unroll
    for (int i = 0; i < 4; ++i) GLDS16(bRow[i] + koffB, ldsB[i]);

    if (AMODE == 1) {
      kc += 64;
      if (kc == gp.cin) {
        kc = 0;
        ++dx;
        ++tap_off;
        if (dx == 3) { dx = 0; tap_off += gp.wpad - 3; }
      }
    }

    __syncthreads();
#pragma unroll
    for (int ks = 0; ks < 2; ++ks) {
      bf16x8 av[4], bv[4];
      const int cc = (ks << 2) + (l >> 4);
#pragma unroll
      for (int mi = 0; mi < 4; ++mi) {
        const int row = wm * 64 + mi * 16 + (l & 15);
        av[mi] = *(const bf16x8*)((const char*)smA + (row << 7) +
                                  ((cc ^ (row & 7)) << 4));
      }
#pragma unroll
      for (int ni = 0; ni < 4; ++ni) {
        const int row = wn * 64 + ni * 16 + (l & 15);
        bv[ni] = *(const bf16x8*)((const char*)smB + (row << 7) +
                                  ((cc ^ (row & 7)) << 4));
      }
#pragma unroll
      for (int mi = 0; mi < 4; ++mi)
#pragma unroll
        for (int ni = 0; ni < 4; ++ni)
          acc[mi][ni] = __builtin_amdgcn_mfma_f32_16x16x32_bf16(
              av[mi], bv[ni], acc[mi][ni], 0, 0, 0);
    }
    __syncthreads();
  }

#pragma unroll
  for (int mi = 0; mi < 4; ++mi) {
#pragma unroll
    for (int ni = 0; ni < 4; ++ni) {
      const int ncol = n0 + wn * 64 + ni * 16 + (l & 15);
      const int mbase = m0 + wm * 64 + mi * 16 + ((l >> 4) << 2);
      const float bv_ = gp.bias ? gp.bias[ncol] : 0.f;

      if constexpr (CW == 3) {
        u16* Cu = (u16*)gp.C + (size_t)b * gp.cBS + (size_t)ncol * 4096 + mbase;
        u16x4 pk;
#pragma unroll
        for (int r = 0; r < 4; ++r) pk[r] = f2b(acc[mi][ni][r] + bv_);
        *(u16x4*)Cu = pk;
      } else if constexpr (CW == 7) {
        u16* base = (u16*)gp.C;
        if (ncol < 256) {
#pragma unroll
          for (int r = 0; r < 4; ++r)
            base[(size_t)b * 1048576 + (size_t)(mbase + r) * 256 + ncol] =
                f2b(acc[mi][ni][r] + bv_);
        } else {
          u16x4 pk;
#pragma unroll
          for (int r = 0; r < 4; ++r) pk[r] = f2b(acc[mi][ni][r] + bv_);
          *(u16x4*)(base + 8388608 + (size_t)b * 1048576 +
                    (size_t)(ncol - 256) * 4096 + mbase) = pk;
        }
      } else {
#pragma unroll
        for (int reg = 0; reg < 4; ++reg) {
          const int mrow = mbase + reg;
          if (mrow >= gp.Mrows) continue;
          float v = acc[mi][ni][reg] * gp.scale + bv_;
          if (RELU) v = v > 0.f ? v : 0.f;
          if constexpr (CW == 0) {
            ((u16*)gp.C)[(size_t)b * gp.cBS + (size_t)mrow * gp.ldc + ncol] =
                f2b(v);
          } else if constexpr (CW == 4) {
            if (mrow == 0) {
              gp.out0[(size_t)b * 256 + ncol] = v;
            } else {
              const int p = mrow - 1, y = p >> 5, x = p & 31;
              ((u16*)gp.C)[(size_t)b * gp.cBS +
                           (size_t)((y + 1) * 34 + (x + 1)) * 256 + ncol] =
                  f2b(v);
            }
          } else if constexpr (CW == 5) {
            ((float*)gp.C)[(size_t)b * gp.cBS + (size_t)mrow * 256 + ncol] = v;
          }
        }
      }
    }
  }
}

// --------------------------- prep / misc kernels ---------------------------

__global__ __launch_bounds__(256) void k_prep_x(const float* __restrict__ x,
                                                u16* __restrict__ o) {
  __shared__ float t[32][65];
  const int b = blockIdx.z, c0 = blockIdx.y << 5, y = blockIdx.x;
  const float* src = x + ((size_t)b * 1280 + c0) * 4096 + (size_t)y * 64;
#pragma unroll
  for (int i = 0; i < 8; ++i) {
    const int idx = threadIdx.x + (i << 8);
    const int c = idx >> 6, xx = idx & 63;
    t[c][xx] = src[(size_t)c * 4096 + xx];
  }
  __syncthreads();
  u16* dst = o + ((size_t)b * 4356 + (size_t)(y + 1) * 66 + 1) * 1280 + c0;
#pragma unroll
  for (int i = 0; i < 8; ++i) {
    const int idx = threadIdx.x + (i << 8);
    const int xx = idx >> 5, c = idx & 31;
    dst[(size_t)xx * 1280 + c] = f2b(t[c][xx]);
  }
}

__global__ __launch_bounds__(256) void k_zero_border(u16* __restrict__ p,
                                                     int P, int C) {
  const int per_img = (4 * P - 4) * C;
  const int total = 8 * per_img;
  for (int idx = blockIdx.x * 256 + threadIdx.x; idx < total;
       idx += gridDim.x * 256) {
    const int b = idx / per_img;
    const int r = idx % per_img;
    const int pix = r / C, c = r % C;
    int y, x;
    const int Pm = P - 1;
    if (pix < P) { y = 0; x = pix; }
    else if (pix < 2 * P) { y = Pm; x = pix - P; }
    else if (pix < 3 * P - 2) { y = pix - 2 * P + 1; x = 0; }
    else { y = pix - (3 * P - 2) + 1; x = Pm; }
    p[((size_t)b * P * P + (size_t)y * P + x) * C + c] = 0;
  }
}

__global__ __launch_bounds__(256) void k_prep_w3(const float* __restrict__ w,
                                                 u16* __restrict__ o, int cin,
                                                 int n) {
  for (int i = blockIdx.x * 256 + threadIdx.x; i < n; i += gridDim.x * 256) {
    const int ci = i % cin;
    const int r = i / cin;
    const int t = r % 9;
    const int co = r / 9;
    o[i] = f2b(w[((size_t)co * cin + ci) * 9 + t]);
  }
}

__global__ __launch_bounds__(256) void k_f2b(const float* __restrict__ x,
                                             u16* __restrict__ o, int n) {
  for (int i = blockIdx.x * 256 + threadIdx.x; i < n; i += gridDim.x * 256)
    o[i] = f2b(x[i]);
}

__global__ __launch_bounds__(256) void k_gn_stats(const float* __restrict__ x,
                                                  float* __restrict__ st) {
  const int b = blockIdx.y;
  const f32x4* xb = (const f32x4*)(x + (size_t)b * 1048576);
  float s = 0.f, s2 = 0.f;
  for (int i = blockIdx.x * 256 + threadIdx.x; i < 262144;
       i += gridDim.x * 256) {
    const f32x4 v = xb[i];
    s += v[0] + v[1] + v[2] + v[3];
    s2 += v[0] * v[0] + v[1] * v[1] + v[2] * v[2] + v[3] * v[3];
  }
#pragma unroll
  for (int o = 32; o; o >>= 1) {
    s += __shfl_down(s, o);
    s2 += __shfl_down(s2, o);
  }
  __shared__ float ls[4], ls2[4];
  const int w = threadIdx.x >> 6;
  if ((threadIdx.x & 63) == 0) { ls[w] = s; ls2[w] = s2; }
  __syncthreads();
  if (threadIdx.x == 0) {
    atomicAdd(&st[b * 2], ls[0] + ls[1] + ls[2] + ls[3]);
    atomicAdd(&st[b * 2 + 1], ls2[0] + ls2[1] + ls2[2] + ls2[3]);
  }
}

template <bool PAD>
__global__ __launch_bounds__(256) void k_gn_norm(const float* __restrict__ x,
                                                 const float* __restrict__ st,
                                                 const float* __restrict__ g,
                                                 const float* __restrict__ bb,
                                                 u16* __restrict__ o) {
  const int b = blockIdx.y;
  const float mu = st[b * 2] * (1.f / 1048576.f);
  const float var = st[b * 2 + 1] * (1.f / 1048576.f) - mu * mu;
  const float rs = rsqrtf(var + 1e-6f);
  const int i4 = blockIdx.x * 256 + threadIdx.x;
  const f32x4 v = ((const f32x4*)(x + (size_t)b * 1048576))[i4];
  const int flat = i4 << 2;
  const int c = flat & 255;
  const int p = flat >> 8;
  const f32x4 gv = *(const f32x4*)(g + c);
  const f32x4 bv = *(const f32x4*)(bb + c);
  u16x4 r;
#pragma unroll
  for (int k = 0; k < 4; ++k) r[k] = f2b((v[k] - mu) * rs * gv[k] + bv[k]);
  size_t oidx;
  if (PAD) {
    const int y = p >> 6, xx = p & 63;
    oidx = ((size_t)b * 4356 + (size_t)(y + 1) * 66 + xx + 1) * 256 + c;
  } else {
    oidx = ((size_t)b * 4096 + p) * 256 + c;
  }
  *(u16x4*)(o + oidx) = r;
}

__global__ __launch_bounds__(256) void k_softmax(u16* __restrict__ s) {
  const size_t row = blockIdx.x;
  u16* p = s + row * 4096;
  const int t = threadIdx.x;
  const short8 r0 = ((const short8*)p)[t];
  const short8 r1 = ((const short8*)p)[t + 256];
  float v[16];
#pragma unroll
  for (int i = 0; i < 8; ++i) {
    v[i] = b2f((u16)r0[i]);
    v[8 + i] = b2f((u16)r1[i]);
  }
  float m = v[0];
#pragma unroll
  for (int i = 1; i < 16; ++i) m = fmaxf(m, v[i]);
#pragma unroll
  for (int o = 32; o; o >>= 1) m = fmaxf(m, __shfl_xor(m, o));
  __shared__ float lm[4], lsum[4];
  const int w = t >> 6;
  if ((t & 63) == 0) lm[w] = m;
  __syncthreads();
  m = fmaxf(fmaxf(lm[0], lm[1]), fmaxf(lm[2], lm[3]));
  float sum = 0.f;
#pragma unroll
  for (int i = 0; i < 16; ++i) {
    v[i] = __expf(v[i] - m);
    sum += v[i];
  }
#pragma unroll
  for (int o = 32; o; o >>= 1) sum += __shfl_xor(sum, o);
  if ((t & 63) == 0) lsum[w] = sum;
  __syncthreads();
  sum = lsum[0] + lsum[1] + lsum[2] + lsum[3];
  const float inv = 1.f / sum;
  short8 o0, o1;
#pragma unroll
  for (int i = 0; i < 8; ++i) {
    o0[i] = (short)f2b(v[i] * inv);
    o1[i] = (short)f2b(v[8 + i] * inv);
  }
  ((short8*)p)[t] = o0;
  ((short8*)p)[t + 256] = o1;
}

__global__ __launch_bounds__(256) void k_resize_add(const float* __restrict__ d0,
                                                    const float* __restrict__ F,
                                                    float* __restrict__ mid) {
  const int i4 = blockIdx.x * 256 + threadIdx.x;
  const int flat = i4 << 2;
  const int c = flat & 255;
  const int p = (flat >> 8) & 4095;
  const int b = flat >> 20;
  const int y = p >> 6, x = p & 63;
  const float fy = y * (31.f / 63.f);
  const int y0 = (int)fy;
  const float wy = fy - y0;
  const int y1 = y0 + 1 > 31 ? 31 : y0 + 1;
  const float fx = x * (31.f / 63.f);
  const int x0 = (int)fx;
  const float wx = fx - x0;
  const int x1 = x0 + 1 > 31 ? 31 : x0 + 1;
  const float* db = d0 + (size_t)b * 262144;
  const f32x4 a = *(const f32x4*)(db + ((size_t)(y0 * 32 + x0) << 8) + c);
  const f32x4 bq = *(const f32x4*)(db + ((size_t)(y0 * 32 + x1) << 8) + c);
  const f32x4 cq = *(const f32x4*)(db + ((size_t)(y1 * 32 + x0) << 8) + c);
  const f32x4 dq = *(const f32x4*)(db + ((size_t)(y1 * 32 + x1) << 8) + c);
  f32x4 r = (a * (1.f - wx) + bq * wx) * (1.f - wy) +
            (cq * (1.f - wx) + dq * wx) * wy;
  r += *(const f32x4*)(F + (size_t)flat);
  *(f32x4*)(mid + (size_t)flat) = r;
}

// ---------------------------------------------------------------------------

extern "C" void kernel_launch(void* const* d_in, const int* in_sizes, int n_in,
                              void* d_out, int out_size, void* d_ws,
                              size_t ws_size, hipStream_t stream) {
  (void)in_sizes; (void)n_in; (void)out_size;

  const float* q   = (const float*)d_in[0];
  const float* xdc = (const float*)d_in[1];
  const float* w1  = (const float*)d_in[2];
  const float* b1  = (const float*)d_in[3];
  const float* w2  = (const float*)d_in[4];
  const float* b2  = (const float*)d_in[5];
  const float* wsc = (const float*)d_in[6];
  const float* bsc = (const float*)d_in[7];
  const float* lng = (const float*)d_in[8];
  const float* lnb = (const float*)d_in[9];
  const float* wk  = (const float*)d_in[10];
  const float* bk  = (const float*)d_in[11];
  const float* wv  = (const float*)d_in[12];
  const float* bv  = (const float*)d_in[13];
  const float* wd0 = (const float*)d_in[14];
  const float* bd0 = (const float*)d_in[15];
  const float* wd1 = (const float*)d_in[16];
  const float* bd1 = (const float*)d_in[17];

  char* ws = (char*)d_ws;
  size_t cur = 0;
  auto alloc = [&](size_t sz) {
    char* p = ws + cur;
    cur += sz;
    return p;
  };
  u16* XPAD = (u16*)alloc(89194496);
  u16* W1R  = (u16*)alloc(5898240);
  u16* W2R  = (u16*)alloc(1179648);
  u16* WSR  = (u16*)alloc(655360);
  u16* WKV  = (u16*)alloc(262144);
  float* BKV = (float*)alloc(2048);
  u16* WD0R = (u16*)alloc(1179648);
  u16* WD1R = (u16*)alloc(1179648);
  u16* SB   = (u16*)alloc(16777216);
  u16* H1   = (u16*)alloc(17842176);
  float* F  = (float*)alloc(33554432);
  u16* FLN  = (u16*)alloc(16777216);
  u16* KT   = (u16*)alloc(16777216);
  u16* V    = (u16*)alloc(16777216);   // value (MUST follow KT)
  u16* QB   = (u16*)alloc(4198400);
  u16* OCP  = (u16*)alloc(4734976);
  float* D0O = (float*)alloc(8388608);
  float* MID = (float*)alloc(33554432);
  u16* G2   = (u16*)alloc(17842176);
  float* ST = (float*)alloc(256);
  u16* SCORES = XPAD;        // alias (X_pad dead after conv1/shortcut)
  float* PART = (float*)FLN; // 67.1MB partials over FLN..D0O (dead until gn1;
                             // QB prep + OCP border-zero MUST run after reduce)
  (void)V;

  if (ws_size < cur) return;

  float* out0 = (float*)d_out;
  float* out1 = (float*)d_out + 2048;

  hipMemsetAsync(ST, 0, 256, stream);
  hipMemcpyAsync(BKV, bk, 1024, hipMemcpyDeviceToDevice, stream);
  hipMemcpyAsync(BKV + 256, bv, 1024, hipMemcpyDeviceToDevice, stream);

  k_zero_border<<<2048, 256, 0, stream>>>(XPAD, 66, 1280);
  k_zero_border<<<1024, 256, 0, stream>>>(H1, 66, 256);
  k_zero_border<<<1024, 256, 0, stream>>>(G2, 66, 256);

  k_prep_x<<<dim3(64, 40, 8), 256, 0, stream>>>(xdc, XPAD);
  k_prep_w3<<<2048, 256, 0, stream>>>(w1, W1R, 1280, 2949120);
  k_prep_w3<<<1024, 256, 0, stream>>>(w2, W2R, 256, 589824);
  k_prep_w3<<<1024, 256, 0, stream>>>(wd0, WD0R, 256, 589824);
  k_prep_w3<<<1024, 256, 0, stream>>>(wd1, WD1R, 256, 589824);
  k_f2b<<<512, 256, 0, stream>>>(wsc, WSR, 327680);
  k_f2b<<<128, 256, 0, stream>>>(wk, WKV, 65536);
  k_f2b<<<128, 256, 0, stream>>>(wv, WKV + 65536, 65536);

  const dim3 g8(32, 1, 8);
  // shortcut 1x1: X_pad(interior) x WSR -> SB (bf16, +bias, no relu)
  {
    GP g{};
    g.A = XPAD; g.B = WSR; g.bias = bsc; g.C = SB;
    g.aBS = 5575680; g.bBS = 0; g.cBS = 1048576;
    g.Ktot = 1280; g.Mrows = 4096; g.ldc = 256;
    g.cin = 1280; g.logW = 6; g.wpad = 66; g.poff = 1; g.scale = 1.f;
    k_gemm8<1, 0, false><<<g8, 512, 0, stream>>>(g);
  }
  // conv1 3x3 via 256x256 split-K kernel -> partials -> H1
  {
    G256 g{};
    g.A = XPAD; g.B = W1R; g.P = PART;
    g.aBS = 5575680; g.Ktot = 11520;
    g.cin = 1280; g.logW = 6; g.wpad = 66; g.poff = 0;
    k_gemm256<<<dim3(16, 2, 8), 512, 0, stream>>>(g);
    k_reduceH1<<<8192, 256, 0, stream>>>(PART, b1, H1);
  }
  // PART region is now dead: safe to populate QB and OCP border
  k_f2b<<<2048, 256, 0, stream>>>(q, QB, 2099200);
  k_zero_border<<<512, 256, 0, stream>>>(OCP, 34, 256);

  // conv2 3x3: H1 x W2R (+bias +SB, relu) -> F fp32
  {
    GP g{};
    g.A = H1; g.B = W2R; g.bias = b2; g.C = F; g.aux = SB;
    g.aBS = 1115136; g.bBS = 0; g.cBS = 1048576; g.auxBS = 1048576;
    g.Ktot = 2304; g.Mrows = 4096; g.ldc = 256;
    g.cin = 256; g.logW = 6; g.wpad = 66; g.poff = 0; g.scale = 1.f;
    k_gemm8<1, 2, false><<<g8, 512, 0, stream>>>(g);
  }
  // gn1
  k_gn_stats<<<dim3(64, 8), 256, 0, stream>>>(F, ST);
  k_gn_norm<false><<<dim3(1024, 8), 256, 0, stream>>>(F, ST, lng, lnb, FLN);
  // fused key+value 1x1
  {
    GP g{};
    g.A = FLN; g.B = WKV; g.bias = BKV; g.C = KT;
    g.aBS = 1048576; g.bBS = 0; g.cBS = 0;
    g.Ktot = 256; g.Mrows = 4096; g.ldc = 256; g.scale = 1.f;
    k_gemm<0, 7, false><<<dim3(32, 4, 8), 256, 0, stream>>>(g);
  }
  // scores
  {
    GP g{};
    g.A = QB; g.B = KT; g.bias = nullptr; g.C = SCORES;
    g.aBS = 262400; g.bBS = 1048576; g.cBS = 4198400;
    g.Ktot = 256; g.Mrows = 1025; g.ldc = 4096; g.scale = 0.0625f;
    k_gemm<0, 0, false><<<dim3(9, 32, 8), 256, 0, stream>>>(g);
  }
  k_softmax<<<8200, 256, 0, stream>>>(SCORES);
  // attn out
  {
    GP g{};
    g.A = SCORES; g.B = V; g.bias = nullptr; g.C = OCP; g.out0 = out0;
    g.aBS = 4198400; g.bBS = 1048576; g.cBS = 295936;
    g.Ktot = 4096; g.Mrows = 1025; g.ldc = 256; g.scale = 1.f;
    k_gemm<0, 4, false><<<dim3(9, 2, 8), 256, 0, stream>>>(g);
  }
  // dh0 3x3 @32x32
  {
    GP g{};
    g.A = OCP; g.B = WD0R; g.bias = bd0; g.C = D0O;
    g.aBS = 295936; g.bBS = 0; g.cBS = 262144;
    g.Ktot = 2304; g.Mrows = 1024; g.ldc = 256;
    g.cin = 256; g.logW = 5; g.wpad = 34; g.poff = 0; g.scale = 1.f;
    k_gemm<1, 5, true><<<dim3(8, 2, 8), 256, 0, stream>>>(g);
  }
  k_resize_add<<<8192, 256, 0, stream>>>(D0O, F, MID);
  k_gn_stats<<<dim3(64, 8), 256, 0, stream>>>(MID, ST + 16);
  k_gn_norm<true><<<dim3(1024, 8), 256, 0, stream>>>(MID, ST + 16, lng, lnb, G2);
  // dh1 3x3: G2 x WD1R, relu(acc+bias)+MID -> out1 (NCHW fp32)
  {
    GP g{};
    g.A = G2; g.B = WD1R; g.bias = bd1; g.C = out1; g.aux = MID;
    g.aBS = 1115136; g.bBS = 0; g.cBS = 1048576; g.auxBS = 1048576;
    g.Ktot = 2304; g.Mrows = 4096; g.ldc = 256;
    g.cin = 256; g.logW = 6; g.wpad = 66; g.poff = 0; g.scale = 1.f;
    k_gemm8<1, 6, false><<<g8, 512, 0, stream>>>(g);
  }
}